// Round 2
// baseline (895.532 us; speedup 1.0000x reference)
//
#include <hip/hip_runtime.h>

typedef unsigned short u16;
typedef float f32x4 __attribute__((ext_vector_type(4)));
typedef short s16x8 __attribute__((ext_vector_type(8)));
typedef __bf16 bf16x8 __attribute__((ext_vector_type(8)));

#define NNODE 50000
#define NEDGE 200000
#define INV_SQRT3 0.57735026918962576f
#define INV_SQRT_FAN 0.0034938562148434216f  /* 1/sqrt(256^2+128^2) */

__device__ inline float b2f(u16 x) {
    unsigned u = ((unsigned)x) << 16;
    return __builtin_bit_cast(float, u);
}
__device__ inline u16 f2b(float f) {
    unsigned u = __builtin_bit_cast(unsigned, f);
    unsigned r = u + 0x7FFFu + ((u >> 16) & 1u);
    return (u16)(r >> 16);
}
__device__ inline float silu(float v) { return v / (1.f + __expf(-v)); }

// dual-mode scalar load: m=1 -> f32 storage, m=0 -> bf16 storage
__device__ inline float ld1(const void* p, long i, int m) {
    return m ? ((const float*)p)[i] : b2f(((const u16*)p)[i]);
}
__device__ inline void stout(void* o, long i, float v, int m) {
    if (m) ((float*)o)[i] = v; else ((u16*)o)[i] = f2b(v);
}

// MFMA wrapper tolerant to either builtin signature (short8 or __bf16x8).
template <typename V>
__device__ auto mfma_sel(V a, V b, f32x4 c, int)
    -> decltype(__builtin_amdgcn_mfma_f32_16x16x32_bf16(a, b, c, 0, 0, 0)) {
    return __builtin_amdgcn_mfma_f32_16x16x32_bf16(a, b, c, 0, 0, 0);
}
template <typename V>
__device__ f32x4 mfma_sel(V a, V b, f32x4 c, long) {
    bf16x8 aa = __builtin_bit_cast(bf16x8, a);
    bf16x8 bb = __builtin_bit_cast(bf16x8, b);
    return __builtin_amdgcn_mfma_f32_16x16x32_bf16(aa, bb, c, 0, 0, 0);
}
__device__ inline f32x4 mfma_bf16(s16x8 a, s16x8 b, f32x4 c) {
    return mfma_sel(a, b, c, 0);
}

// ---------------- detect input storage dtype ----------------
// even-indexed u16: bf16 storage -> exponent byte bf16-plausible (~100%);
// f32 storage -> low mantissa half, uniform (~8%).
__global__ __launch_bounds__(256) void detect_k(const void* __restrict__ h, int* __restrict__ flag) {
    int t = threadIdx.x;
    u16 w = ((const u16*)h)[2 * t];
    int tb = (w >> 8) & 0x7F;
    bool pl = (tb >= 0x38 && tb <= 0x41);
    unsigned long long b = __ballot(pl);
    __shared__ int cnt[4];
    if ((t & 63) == 0) cnt[t >> 6] = __popcll(b);
    __syncthreads();
    if (t == 0) {
        int s = cnt[0] + cnt[1] + cnt[2] + cnt[3];
        flag[0] = (s < 128) ? 1 : 0;  // 1 = f32 storage
    }
}

// ---------------- prep: transposes / packs / w_eff ----------------
__global__ __launch_bounds__(256) void prep_misc_k(
    const void* __restrict__ W00, const void* __restrict__ W11,
    const void* __restrict__ bW1, const void* __restrict__ Wv,
    const void* __restrict__ Wcoord,
    u16* __restrict__ W00T, u16* __restrict__ W11T,
    u16* __restrict__ W1eh, u16* __restrict__ W1el,
    float* __restrict__ w1tp, float* __restrict__ w_eff,
    const int* __restrict__ mflag)
{
    const int m = *mflag;
    int u = blockIdx.x * 256 + threadIdx.x;
    if (u < 65536) {                 // W00T[j][i] = W00[i][j]
        int j = u >> 8, i = u & 255;
        W00T[u] = f2b(ld1(W00, (long)i * 256 + j, m));
    } else if (u < 81920) {          // W11T[d][c] = W11[c][d]
        int v = u - 65536; int d = v >> 7, c = v & 127;
        W11T[v] = f2b(ld1(W11, (long)c * 128 + d, m));
    } else if (u < 98304) {          // W1e split: bond_W1[hd][1+k]
        int v = u - 81920; int hd = v >> 6, k = v & 63;
        float x = ld1(bW1, (long)hd * 65 + 1 + k, m);
        u16 hi = f2b(x);
        W1eh[v] = hi;
        W1el[v] = f2b(x - b2f(hi));
    } else if (u < 98560) {          // w1tp[hd] = bond_W1[hd][0]
        int hd = u - 98304;
        w1tp[hd] = ld1(bW1, (long)hd * 65, m);
    } else if (u < 98688) {          // w_eff[c] = sum_d Wcoord[d]*Wv[d][c]
        int c = u - 98560;
        float acc = 0.f;
        for (int d = 0; d < 128; ++d)
            acc += ld1(Wcoord, d, m) * ld1(Wv, (long)d * 128 + c, m);
        w_eff[c] = acc;
    }
}

// W1s = atom_W1 @ Ws_w (fold Ws into atom layer1), split bf16; b1p = atom_W1@Ws_b + atom_b1
__global__ __launch_bounds__(256) void prep_w1s_k(
    const void* __restrict__ aW1, const void* __restrict__ Wsw,
    const void* __restrict__ Wsb, const void* __restrict__ ab1,
    u16* __restrict__ W1sh, u16* __restrict__ W1sl, float* __restrict__ b1p,
    const int* __restrict__ mflag)
{
    const int m = *mflag;
    int hd = blockIdx.x, s = threadIdx.x;
    float acc = 0.f;
    for (int j = 0; j < 256; ++j)
        acc += ld1(aW1, (long)hd * 256 + j, m) * ld1(Wsw, (long)j * 256 + s, m);
    u16 hi = f2b(acc);
    W1sh[hd * 256 + s] = hi;
    W1sl[hd * 256 + s] = f2b(acc - b2f(hi));
    if (s == 0) {
        float b = ld1(ab1, hd, m);
        for (int j = 0; j < 256; ++j)
            b += ld1(aW1, (long)hd * 256 + j, m) * ld1(Wsb, j, m);
        b1p[hd] = b;
    }
}

// ---------------- GEMM into PQ: C[grow*ldc + cmul*col + coff + z] = scale * (A @ Bt^T) ----------------
// SA=true: A element [row][k] = Af[row*lda + aoff + z + 3*k] (stride-3 gather, batch z)
template <bool SA>
__global__ __launch_bounds__(256) void gemm_pq_k(
    const void* __restrict__ A, int lda, int aoff,
    const u16* __restrict__ Bt, int ldb,
    u16* __restrict__ C, int ldc, int cmul, int coff,
    float scale, int M, int K, const int* __restrict__ mflag)
{
    const int m = *mflag;
    __shared__ __align__(16) u16 As[128][40];
    __shared__ __align__(16) u16 Bs[128][40];
    int tid = threadIdx.x;
    int lane = tid & 63, wave = tid >> 6;
    int wm = (wave & 1) * 64, wn = (wave >> 1) * 64;
    int lm = lane & 15, quad = lane >> 4;
    int bm0 = blockIdx.y * 128, bn0 = blockIdx.x * 128;
    int z = blockIdx.z;
    f32x4 acc[4][4] = {};
    int r = tid >> 2, c = tid & 3;  // each (r,c) covers elements c*8 .. c*8+7
    for (int k0 = 0; k0 < K; k0 += 32) {
#pragma unroll
        for (int p = 0; p < 2; ++p) {
            int row = p * 64 + r;
            int grow = bm0 + row;
            u16 tmp[8];
            if (grow < M) {
                if (SA) {
                    long base = (long)grow * lda + aoff + z + 3L * (k0 + c * 8);
#pragma unroll
                    for (int j = 0; j < 8; ++j) tmp[j] = f2b(ld1(A, base + 3 * j, m));
                } else {
                    long base = (long)grow * lda + aoff + k0 + c * 8;
                    if (m) {
                        float4 a0 = *(const float4*)((const float*)A + base);
                        float4 a1 = *(const float4*)((const float*)A + base + 4);
                        tmp[0] = f2b(a0.x); tmp[1] = f2b(a0.y); tmp[2] = f2b(a0.z); tmp[3] = f2b(a0.w);
                        tmp[4] = f2b(a1.x); tmp[5] = f2b(a1.y); tmp[6] = f2b(a1.z); tmp[7] = f2b(a1.w);
                    } else {
                        *(ushort4*)&tmp[0] = *(const ushort4*)((const u16*)A + base);
                        *(ushort4*)&tmp[4] = *(const ushort4*)((const u16*)A + base + 4);
                    }
                }
            } else {
#pragma unroll
                for (int j = 0; j < 8; ++j) tmp[j] = 0;
            }
            *(ushort4*)&As[row][c * 8]     = *(ushort4*)&tmp[0];
            *(ushort4*)&As[row][c * 8 + 4] = *(ushort4*)&tmp[4];
            long bb = (long)(bn0 + row) * ldb + k0 + c * 8;
            *(ushort4*)&Bs[row][c * 8]     = *(const ushort4*)(Bt + bb);
            *(ushort4*)&Bs[row][c * 8 + 4] = *(const ushort4*)(Bt + bb + 4);
        }
        __syncthreads();
        s16x8 af[4], bfr[4];
#pragma unroll
        for (int t = 0; t < 4; ++t) {
            af[t]  = *(const s16x8*)&As[wm + t * 16 + lm][quad * 8];
            bfr[t] = *(const s16x8*)&Bs[wn + t * 16 + lm][quad * 8];
        }
#pragma unroll
        for (int i = 0; i < 4; ++i)
#pragma unroll
            for (int j = 0; j < 4; ++j)
                acc[i][j] = mfma_bf16(af[i], bfr[j], acc[i][j]);
        __syncthreads();
    }
#pragma unroll
    for (int j = 0; j < 4; ++j) {
        int col = bn0 + wn + j * 16 + lm;
#pragma unroll
        for (int i = 0; i < 4; ++i)
#pragma unroll
            for (int rr = 0; rr < 4; ++rr) {
                int grow = bm0 + wm + i * 16 + quad * 4 + rr;
                if (grow < M)
                    C[(long)grow * ldc + cmul * col + coff + z] = f2b(scale * acc[i][j][rr]);
            }
    }
}

// ---------------- fused MLP with split-bf16 layer1 ----------------
// out = silu(A@W1^T [+tp*w1tp] + b1) @ W2^T + b2 ;  64 rows/block, hidden=256
template <int KDIM, int NOUT, bool BOND>
__global__ __launch_bounds__(256) void mlp_k(
    const void* __restrict__ A, int lda,
    const u16* __restrict__ Bh, const u16* __restrict__ Bl,
    const float* __restrict__ b1p, const void* __restrict__ b1v,
    const void* __restrict__ W2v, const void* __restrict__ b2v,
    const float* __restrict__ tp, const float* __restrict__ w1tp,
    void* __restrict__ out, long ooff, int M, const int* __restrict__ mflag)
{
    const int m = *mflag;
    __shared__ __align__(16) u16 Ah[64][40], Al[64][40];
    __shared__ __align__(16) u16 Bsh[256][40], Bsl[256][40];
    __shared__ __align__(16) u16 hidS[64][264];
    __shared__ float W2s[NOUT][257];
    int tid = threadIdx.x;
    int lane = tid & 63, w = tid >> 6;
    int lm = lane & 15, quad = lane >> 4;
    int bm0 = blockIdx.x * 64;
    for (int idx = tid; idx < NOUT * 256; idx += 256)
        W2s[idx >> 8][idx & 255] = ld1(W2v, idx, m);
    f32x4 acc[16] = {};
    int r = tid >> 2, c = tid & 3;
    for (int k0 = 0; k0 < KDIM; k0 += 32) {
        {   // A tile, 64 x 32, split hi/lo
            int grow = bm0 + r;
            u16 th[8], tl[8];
            if (grow < M) {
                long base = (long)grow * lda + k0 + c * 8;
                if (m) {
                    float4 a0 = *(const float4*)((const float*)A + base);
                    float4 a1 = *(const float4*)((const float*)A + base + 4);
                    float v[8] = {a0.x, a0.y, a0.z, a0.w, a1.x, a1.y, a1.z, a1.w};
#pragma unroll
                    for (int j = 0; j < 8; ++j) {
                        th[j] = f2b(v[j]);
                        tl[j] = f2b(v[j] - b2f(th[j]));
                    }
                } else {
                    *(ushort4*)&th[0] = *(const ushort4*)((const u16*)A + base);
                    *(ushort4*)&th[4] = *(const ushort4*)((const u16*)A + base + 4);
#pragma unroll
                    for (int j = 0; j < 8; ++j) tl[j] = 0;
                }
            } else {
#pragma unroll
                for (int j = 0; j < 8; ++j) { th[j] = 0; tl[j] = 0; }
            }
            *(ushort4*)&Ah[r][c * 8]     = *(ushort4*)&th[0];
            *(ushort4*)&Ah[r][c * 8 + 4] = *(ushort4*)&th[4];
            *(ushort4*)&Al[r][c * 8]     = *(ushort4*)&tl[0];
            *(ushort4*)&Al[r][c * 8 + 4] = *(ushort4*)&tl[4];
        }
#pragma unroll
        for (int p = 0; p < 4; ++p) {  // B tiles: 256 x 32 (hi and lo)
            int n = p * 64 + r;
            long bb = (long)n * KDIM + k0 + c * 8;
            *(ushort4*)&Bsh[n][c * 8]     = *(const ushort4*)(Bh + bb);
            *(ushort4*)&Bsh[n][c * 8 + 4] = *(const ushort4*)(Bh + bb + 4);
            *(ushort4*)&Bsl[n][c * 8]     = *(const ushort4*)(Bl + bb);
            *(ushort4*)&Bsl[n][c * 8 + 4] = *(const ushort4*)(Bl + bb + 4);
        }
        __syncthreads();
        s16x8 ah = *(const s16x8*)&Ah[w * 16 + lm][quad * 8];
        s16x8 al = *(const s16x8*)&Al[w * 16 + lm][quad * 8];
#pragma unroll
        for (int tn = 0; tn < 16; ++tn) {
            s16x8 bh = *(const s16x8*)&Bsh[tn * 16 + lm][quad * 8];
            s16x8 bl = *(const s16x8*)&Bsl[tn * 16 + lm][quad * 8];
            acc[tn] = mfma_bf16(ah, bh, acc[tn]);
            acc[tn] = mfma_bf16(ah, bl, acc[tn]);
            if (m) acc[tn] = mfma_bf16(al, bh, acc[tn]);
        }
        __syncthreads();
    }
    float tpv[4] = {0.f, 0.f, 0.f, 0.f};
    if (BOND) {
#pragma unroll
        for (int rr = 0; rr < 4; ++rr) {
            int grow = bm0 + w * 16 + quad * 4 + rr;
            tpv[rr] = (grow < M) ? tp[grow] : 0.f;
        }
    }
#pragma unroll
    for (int tn = 0; tn < 16; ++tn) {
        int col = tn * 16 + lm;
        float bb = BOND ? ld1(b1v, col, m) : b1p[col];
        float wtp = BOND ? w1tp[col] : 0.f;
#pragma unroll
        for (int rr = 0; rr < 4; ++rr) {
            int rl = w * 16 + quad * 4 + rr;
            float v = acc[tn][rr] + bb;
            if (BOND) v += tpv[rr] * wtp;
            hidS[rl][col] = f2b(silu(v));
        }
    }
    __syncthreads();
    for (int u = tid; u < 64 * NOUT; u += 256) {
        int rl = u / NOUT, o = u - rl * NOUT;
        int grow = bm0 + rl;
        if (grow >= M) continue;
        float facc = ld1(b2v, o, m);
#pragma unroll 8
        for (int hh = 0; hh < 256; ++hh)
            facc += b2f(hidS[rl][hh]) * W2s[o][hh];
        stout(out, ooff + (long)grow * NOUT + o, facc, m);
    }
}

// ---------------- tp: wave-per-edge contiguous 640-dot ----------------
__global__ __launch_bounds__(256) void tp_k(
    const int* __restrict__ ei, const void* __restrict__ h,
    const u16* __restrict__ PQ, float* __restrict__ tp,
    const int* __restrict__ mflag)
{
    const int m = *mflag;
    int wave = threadIdx.x >> 6, lane = threadIdx.x & 63;
    int e = blockIdx.x * 4 + wave;
    if (e >= NEDGE) return;
    int row = ei[e], col = ei[NEDGE + e];
    const u16* pq = PQ + (long)row * 640;
    float acc = 0.f;
    if (m) {
        const float* hp = (const float*)h + (long)col * 640;
#pragma unroll
        for (int t = 0; t < 10; ++t) { int j = lane + 64 * t; acc += b2f(pq[j]) * hp[j]; }
    } else {
        const u16* hp = (const u16*)h + (long)col * 640;
#pragma unroll
        for (int t = 0; t < 10; ++t) { int j = lane + 64 * t; acc += b2f(pq[j]) * b2f(hp[j]); }
    }
#pragma unroll
    for (int off = 32; off > 0; off >>= 1) acc += __shfl_down(acc, off);
    if (lane == 0) tp[e] = acc;
}

// ---------------- r0: thread per (n,i) ----------------
__global__ __launch_bounds__(256) void r0_k(
    const void* __restrict__ h, const float* __restrict__ w_eff,
    void* __restrict__ out, const int* __restrict__ mflag)
{
    const int m = *mflag;
    int t = blockIdx.x * 256 + threadIdx.x;
    if (t >= 150000) return;
    int n = t / 3, i = t - n * 3;
    long base = (long)n * 640 + 256 + i;
    float acc = 0.f;
#pragma unroll 4
    for (int c = 0; c < 128; ++c) acc += w_eff[c] * ld1(h, base + 3L * c, m);
    stout(out, 800000L + t, acc, m);
}

extern "C" void kernel_launch(void* const* d_in, const int* in_sizes, int n_in,
                              void* d_out, int out_size, void* d_ws, size_t ws_size,
                              hipStream_t stream) {
    (void)in_sizes; (void)n_in; (void)out_size; (void)ws_size;
    const void* h      = d_in[0];
    const void* e_fin  = d_in[1];
    const int*  ei     = (const int*)d_in[4];
    const void* Ws_w   = d_in[5];
    const void* Ws_b   = d_in[6];
    const void* Wv     = d_in[7];
    const void* Wcoord = d_in[8];
    const void* W00    = d_in[9];
    const void* W11    = d_in[10];
    const void* aW1    = d_in[11];
    const void* ab1    = d_in[12];
    const void* aW2    = d_in[13];
    const void* ab2    = d_in[14];
    const void* bW1    = d_in[15];
    const void* bb1    = d_in[16];
    const void* bW2    = d_in[17];
    const void* bb2    = d_in[18];

    char* ws = (char*)d_ws;
    int*   mflag = (int*)(ws + 0);
    float* w1tp  = (float*)(ws + 512);
    float* w_eff = (float*)(ws + 1536);
    float* b1p   = (float*)(ws + 2048);
    u16*   W00T  = (u16*)(ws + 3072);
    u16*   W11T  = (u16*)(ws + 134144);
    u16*   W1eh  = (u16*)(ws + 166912);
    u16*   W1el  = (u16*)(ws + 199680);
    u16*   W1sh  = (u16*)(ws + 232448);
    u16*   W1sl  = (u16*)(ws + 363520);
    float* tp    = (float*)(ws + 494592);
    u16*   PQ    = (u16*)(ws + 1294592);   // 50000 x 640 bf16 -> ends ~65.3 MB

    detect_k<<<1, 256, 0, stream>>>(h, mflag);
    prep_misc_k<<<386, 256, 0, stream>>>(W00, W11, bW1, Wv, Wcoord,
                                         W00T, W11T, W1eh, W1el, w1tp, w_eff, mflag);
    prep_w1s_k<<<256, 256, 0, stream>>>(aW1, Ws_w, Ws_b, ab1, W1sh, W1sl, b1p, mflag);
    // PQ[:, :256] = INV_SQRT_FAN * (Xs @ W00)
    gemm_pq_k<false><<<dim3(2, 391, 1), 256, 0, stream>>>(
        h, 640, 0, W00T, 256, PQ, 640, 1, 0, INV_SQRT_FAN, NNODE, 256, mflag);
    // PQ[:, 256+3d+i] = INV_SQRT_FAN/sqrt(3) * (Xv_i @ W11)[.,d]
    gemm_pq_k<true><<<dim3(1, 391, 3), 256, 0, stream>>>(
        h, 640, 256, W11T, 128, PQ, 640, 3, 256, INV_SQRT_FAN * INV_SQRT3, NNODE, 128, mflag);
    // atom logits (Ws folded into layer1)
    mlp_k<256, 16, false><<<782, 256, 0, stream>>>(
        h, 640, W1sh, W1sl, b1p, nullptr, aW2, ab2, nullptr, nullptr,
        d_out, 0L, NNODE, mflag);
    // predicted_r0
    r0_k<<<586, 256, 0, stream>>>(h, w_eff, d_out, mflag);
    // tp per edge
    tp_k<<<50000, 256, 0, stream>>>(ei, h, PQ, tp, mflag);
    // bond logits
    mlp_k<64, 5, true><<<3125, 256, 0, stream>>>(
        e_fin, 64, W1eh, W1el, nullptr, bb1, bW2, bb2, tp, w1tp,
        d_out, 950000L, NEDGE, mflag);
}

// Round 3
// 840.829 us; speedup vs baseline: 1.0651x; 1.0651x over previous
//
#include <hip/hip_runtime.h>

typedef unsigned short u16;
typedef float f32x4 __attribute__((ext_vector_type(4)));
typedef short s16x8 __attribute__((ext_vector_type(8)));
typedef __bf16 bf16x8 __attribute__((ext_vector_type(8)));

#define NNODE 50000
#define NEDGE 200000
#define INV_SQRT3 0.57735026918962576f
#define INV_SQRT_FAN 0.0034938562148434216f  /* 1/sqrt(256^2+128^2) */

__device__ inline float b2f(u16 x) {
    unsigned u = ((unsigned)x) << 16;
    return __builtin_bit_cast(float, u);
}
__device__ inline u16 f2b(float f) {
    unsigned u = __builtin_bit_cast(unsigned, f);
    unsigned r = u + 0x7FFFu + ((u >> 16) & 1u);
    return (u16)(r >> 16);
}
__device__ inline float silu(float v) { return v / (1.f + __expf(-v)); }

// dual-mode scalar load: m=1 -> f32 storage, m=0 -> bf16 storage
__device__ inline float ld1(const void* p, long i, int m) {
    return m ? ((const float*)p)[i] : b2f(((const u16*)p)[i]);
}
__device__ inline void stout(void* o, long i, float v, int m) {
    if (m) ((float*)o)[i] = v; else ((u16*)o)[i] = f2b(v);
}

// MFMA wrapper tolerant to either builtin signature (short8 or __bf16x8).
template <typename V>
__device__ auto mfma_sel(V a, V b, f32x4 c, int)
    -> decltype(__builtin_amdgcn_mfma_f32_16x16x32_bf16(a, b, c, 0, 0, 0)) {
    return __builtin_amdgcn_mfma_f32_16x16x32_bf16(a, b, c, 0, 0, 0);
}
template <typename V>
__device__ f32x4 mfma_sel(V a, V b, f32x4 c, long) {
    bf16x8 aa = __builtin_bit_cast(bf16x8, a);
    bf16x8 bb = __builtin_bit_cast(bf16x8, b);
    return __builtin_amdgcn_mfma_f32_16x16x32_bf16(aa, bb, c, 0, 0, 0);
}
__device__ inline f32x4 mfma_bf16(s16x8 a, s16x8 b, f32x4 c) {
    return mfma_sel(a, b, c, 0);
}

// ---------------- detect input storage dtype ----------------
__global__ __launch_bounds__(256) void detect_k(const void* __restrict__ h, int* __restrict__ flag) {
    int t = threadIdx.x;
    u16 w = ((const u16*)h)[2 * t];
    int tb = (w >> 8) & 0x7F;
    bool pl = (tb >= 0x38 && tb <= 0x41);
    unsigned long long b = __ballot(pl);
    __shared__ int cnt[4];
    if ((t & 63) == 0) cnt[t >> 6] = __popcll(b);
    __syncthreads();
    if (t == 0) {
        int s = cnt[0] + cnt[1] + cnt[2] + cnt[3];
        flag[0] = (s < 128) ? 1 : 0;  // 1 = f32 storage
    }
}

// ---------------- prep: transposes / splits / w_eff ----------------
__global__ __launch_bounds__(256) void prep_misc_k(
    const void* __restrict__ W00, const void* __restrict__ W11,
    const void* __restrict__ bW1, const void* __restrict__ Wv,
    const void* __restrict__ Wcoord, const void* __restrict__ aW2,
    const void* __restrict__ bW2,
    u16* __restrict__ W00T, u16* __restrict__ W11T,
    u16* __restrict__ W1eh, u16* __restrict__ W1el,
    float* __restrict__ w1tp, float* __restrict__ w_eff,
    u16* __restrict__ W2ah, u16* __restrict__ W2al,
    u16* __restrict__ W2bh, u16* __restrict__ W2bl,
    const int* __restrict__ mflag)
{
    const int m = *mflag;
    int u = blockIdx.x * 256 + threadIdx.x;
    if (u < 65536) {                 // W00T[j][i] = W00[i][j]
        int j = u >> 8, i = u & 255;
        W00T[u] = f2b(ld1(W00, (long)i * 256 + j, m));
    } else if (u < 81920) {          // W11T[d][c] = W11[c][d]
        int v = u - 65536; int d = v >> 7, c = v & 127;
        W11T[v] = f2b(ld1(W11, (long)c * 128 + d, m));
    } else if (u < 98304) {          // W1e split: bond_W1[hd][1+k]
        int v = u - 81920; int hd = v >> 6, k = v & 63;
        float x = ld1(bW1, (long)hd * 65 + 1 + k, m);
        u16 hi = f2b(x);
        W1eh[v] = hi;
        W1el[v] = f2b(x - b2f(hi));
    } else if (u < 98560) {          // w1tp[hd] = bond_W1[hd][0]
        int hd = u - 98304;
        w1tp[hd] = ld1(bW1, (long)hd * 65, m);
    } else if (u < 98688) {          // w_eff[c] = sum_d Wcoord[d]*Wv[d][c]
        int c = u - 98560;
        float acc = 0.f;
        for (int d = 0; d < 128; ++d)
            acc += ld1(Wcoord, d, m) * ld1(Wv, (long)d * 128 + c, m);
        w_eff[c] = acc;
    } else if (u < 102784) {         // atom W2 split (16x256)
        int v = u - 98688;
        float x = ld1(aW2, v, m);
        u16 hi = f2b(x);
        W2ah[v] = hi;
        W2al[v] = f2b(x - b2f(hi));
    } else if (u < 106880) {         // bond W2 padded to 16x256, split
        int v = u - 102784; int o = v >> 8, k = v & 255;
        float x = (o < 5) ? ld1(bW2, (long)o * 256 + k, m) : 0.f;
        u16 hi = f2b(x);
        W2bh[v] = hi;
        W2bl[v] = f2b(x - b2f(hi));
    }
}

// W1s = atom_W1 @ Ws_w (fold Ws into atom layer1), split bf16; b1p = atom_W1@Ws_b + atom_b1
__global__ __launch_bounds__(256) void prep_w1s_k(
    const void* __restrict__ aW1, const void* __restrict__ Wsw,
    const void* __restrict__ Wsb, const void* __restrict__ ab1,
    u16* __restrict__ W1sh, u16* __restrict__ W1sl, float* __restrict__ b1p,
    const int* __restrict__ mflag)
{
    const int m = *mflag;
    int hd = blockIdx.x, s = threadIdx.x;
    float acc = 0.f;
    for (int j = 0; j < 256; ++j)
        acc += ld1(aW1, (long)hd * 256 + j, m) * ld1(Wsw, (long)j * 256 + s, m);
    u16 hi = f2b(acc);
    W1sh[hd * 256 + s] = hi;
    W1sl[hd * 256 + s] = f2b(acc - b2f(hi));
    if (s == 0) {
        float b = ld1(ab1, hd, m);
        for (int j = 0; j < 256; ++j)
            b += ld1(aW1, (long)hd * 256 + j, m) * ld1(Wsb, j, m);
        b1p[hd] = b;
    }
}

// ---------------- GEMM into PQ (from round 2, unchanged) ----------------
template <bool SA>
__global__ __launch_bounds__(256) void gemm_pq_k(
    const void* __restrict__ A, int lda, int aoff,
    const u16* __restrict__ Bt, int ldb,
    u16* __restrict__ C, int ldc, int cmul, int coff,
    float scale, int M, int K, const int* __restrict__ mflag)
{
    const int m = *mflag;
    __shared__ __align__(16) u16 As[128][40];
    __shared__ __align__(16) u16 Bs[128][40];
    int tid = threadIdx.x;
    int lane = tid & 63, wave = tid >> 6;
    int wm = (wave & 1) * 64, wn = (wave >> 1) * 64;
    int lm = lane & 15, quad = lane >> 4;
    int bm0 = blockIdx.y * 128, bn0 = blockIdx.x * 128;
    int z = blockIdx.z;
    f32x4 acc[4][4] = {};
    int r = tid >> 2, c = tid & 3;
    for (int k0 = 0; k0 < K; k0 += 32) {
#pragma unroll
        for (int p = 0; p < 2; ++p) {
            int row = p * 64 + r;
            int grow = bm0 + row;
            u16 tmp[8];
            if (grow < M) {
                if (SA) {
                    long base = (long)grow * lda + aoff + z + 3L * (k0 + c * 8);
#pragma unroll
                    for (int j = 0; j < 8; ++j) tmp[j] = f2b(ld1(A, base + 3 * j, m));
                } else {
                    long base = (long)grow * lda + aoff + k0 + c * 8;
                    if (m) {
                        float4 a0 = *(const float4*)((const float*)A + base);
                        float4 a1 = *(const float4*)((const float*)A + base + 4);
                        tmp[0] = f2b(a0.x); tmp[1] = f2b(a0.y); tmp[2] = f2b(a0.z); tmp[3] = f2b(a0.w);
                        tmp[4] = f2b(a1.x); tmp[5] = f2b(a1.y); tmp[6] = f2b(a1.z); tmp[7] = f2b(a1.w);
                    } else {
                        *(ushort4*)&tmp[0] = *(const ushort4*)((const u16*)A + base);
                        *(ushort4*)&tmp[4] = *(const ushort4*)((const u16*)A + base + 4);
                    }
                }
            } else {
#pragma unroll
                for (int j = 0; j < 8; ++j) tmp[j] = 0;
            }
            *(ushort4*)&As[row][c * 8]     = *(ushort4*)&tmp[0];
            *(ushort4*)&As[row][c * 8 + 4] = *(ushort4*)&tmp[4];
            long bb = (long)(bn0 + row) * ldb + k0 + c * 8;
            *(ushort4*)&Bs[row][c * 8]     = *(const ushort4*)(Bt + bb);
            *(ushort4*)&Bs[row][c * 8 + 4] = *(const ushort4*)(Bt + bb + 4);
        }
        __syncthreads();
        s16x8 af[4], bfr[4];
#pragma unroll
        for (int t = 0; t < 4; ++t) {
            af[t]  = *(const s16x8*)&As[wm + t * 16 + lm][quad * 8];
            bfr[t] = *(const s16x8*)&Bs[wn + t * 16 + lm][quad * 8];
        }
#pragma unroll
        for (int i = 0; i < 4; ++i)
#pragma unroll
            for (int j = 0; j < 4; ++j)
                acc[i][j] = mfma_bf16(af[i], bfr[j], acc[i][j]);
        __syncthreads();
    }
#pragma unroll
    for (int j = 0; j < 4; ++j) {
        int col = bn0 + wn + j * 16 + lm;
#pragma unroll
        for (int i = 0; i < 4; ++i)
#pragma unroll
            for (int rr = 0; rr < 4; ++rr) {
                int grow = bm0 + wm + i * 16 + quad * 4 + rr;
                if (grow < M)
                    C[(long)grow * ldc + cmul * col + coff + z] = f2b(scale * acc[i][j][rr]);
            }
    }
}

// ---------------- MLP layer1: hid = silu(A@W1^T [+tp*w1tp] + b1), bf16 out ----------------
// 128x128 tiles over N=256 (gridDim.x==2). lo_mode: 1 = B-lo always, 0 = B-lo iff m.
template <int KDIM, bool BOND>
__global__ __launch_bounds__(256) void mlp_l1_k(
    const void* __restrict__ A, int lda, long row0,
    const u16* __restrict__ Bh, const u16* __restrict__ Bl,
    const float* __restrict__ b1p, const void* __restrict__ b1v,
    const float* __restrict__ tp, const float* __restrict__ w1tp,
    u16* __restrict__ hid, int M, int lo_mode, const int* __restrict__ mflag)
{
    const int m = *mflag;
    const bool use_lo = (lo_mode != 0) || (m != 0);
    __shared__ __align__(16) u16 Ah[128][40], Al[128][40];
    __shared__ __align__(16) u16 Bsh[128][40], Bsl[128][40];
    int tid = threadIdx.x;
    int lane = tid & 63, wave = tid >> 6;
    int wm = (wave & 1) * 64, wn = (wave >> 1) * 64;
    int lm = lane & 15, quad = lane >> 4;
    int bm0 = blockIdx.y * 128, bn0 = blockIdx.x * 128;
    f32x4 acc[4][4] = {};
    int r = tid >> 2, c = tid & 3;
    for (int k0 = 0; k0 < KDIM; k0 += 32) {
#pragma unroll
        for (int p = 0; p < 2; ++p) {
            int row = p * 64 + r;
            int grow = bm0 + row;
            u16 th[8], tl[8];
            if (grow < M) {
                long base = (long)(row0 + grow) * lda + k0 + c * 8;
                if (m) {
                    float4 a0 = *(const float4*)((const float*)A + base);
                    float4 a1 = *(const float4*)((const float*)A + base + 4);
                    float v[8] = {a0.x, a0.y, a0.z, a0.w, a1.x, a1.y, a1.z, a1.w};
#pragma unroll
                    for (int j = 0; j < 8; ++j) { th[j] = f2b(v[j]); tl[j] = f2b(v[j] - b2f(th[j])); }
                } else {
                    *(ushort4*)&th[0] = *(const ushort4*)((const u16*)A + base);
                    *(ushort4*)&th[4] = *(const ushort4*)((const u16*)A + base + 4);
                }
            } else {
#pragma unroll
                for (int j = 0; j < 8; ++j) { th[j] = 0; tl[j] = 0; }
            }
            *(ushort4*)&Ah[row][c * 8]     = *(ushort4*)&th[0];
            *(ushort4*)&Ah[row][c * 8 + 4] = *(ushort4*)&th[4];
            if (m) {
                *(ushort4*)&Al[row][c * 8]     = *(ushort4*)&tl[0];
                *(ushort4*)&Al[row][c * 8 + 4] = *(ushort4*)&tl[4];
            }
            long bb = (long)(bn0 + row) * KDIM + k0 + c * 8;
            *(ushort4*)&Bsh[row][c * 8]     = *(const ushort4*)(Bh + bb);
            *(ushort4*)&Bsh[row][c * 8 + 4] = *(const ushort4*)(Bh + bb + 4);
            if (use_lo) {
                *(ushort4*)&Bsl[row][c * 8]     = *(const ushort4*)(Bl + bb);
                *(ushort4*)&Bsl[row][c * 8 + 4] = *(const ushort4*)(Bl + bb + 4);
            }
        }
        __syncthreads();
        s16x8 af[4], bfh[4];
#pragma unroll
        for (int t = 0; t < 4; ++t) {
            af[t]  = *(const s16x8*)&Ah[wm + t * 16 + lm][quad * 8];
            bfh[t] = *(const s16x8*)&Bsh[wn + t * 16 + lm][quad * 8];
        }
#pragma unroll
        for (int i = 0; i < 4; ++i)
#pragma unroll
            for (int j = 0; j < 4; ++j)
                acc[i][j] = mfma_bf16(af[i], bfh[j], acc[i][j]);
        if (use_lo) {
#pragma unroll
            for (int j = 0; j < 4; ++j) {
                s16x8 bl = *(const s16x8*)&Bsl[wn + j * 16 + lm][quad * 8];
#pragma unroll
                for (int i = 0; i < 4; ++i)
                    acc[i][j] = mfma_bf16(af[i], bl, acc[i][j]);
            }
        }
        if (m) {
#pragma unroll
            for (int i = 0; i < 4; ++i) {
                s16x8 al = *(const s16x8*)&Al[wm + i * 16 + lm][quad * 8];
#pragma unroll
                for (int j = 0; j < 4; ++j) {
                    s16x8 bh = *(const s16x8*)&Bsh[wn + j * 16 + lm][quad * 8];
                    acc[i][j] = mfma_bf16(al, bh, acc[i][j]);
                }
            }
        }
        __syncthreads();
    }
#pragma unroll
    for (int j = 0; j < 4; ++j) {
        int col = bn0 + wn + j * 16 + lm;
        float bb = BOND ? ld1(b1v, col, m) : b1p[col];
        float wtp = BOND ? w1tp[col] : 0.f;
#pragma unroll
        for (int i = 0; i < 4; ++i)
#pragma unroll
            for (int rr = 0; rr < 4; ++rr) {
                int grow = bm0 + wm + i * 16 + quad * 4 + rr;
                if (grow < M) {
                    float v = acc[i][j][rr] + bb;
                    if (BOND) v += tp[row0 + grow] * wtp;
                    hid[(long)grow * 256 + col] = f2b(silu(v));
                }
            }
    }
}

// ---------------- MLP layer2: out = hid @ W2^T + b2, wave per 16-row tile, no LDS ----------------
template <int NOUT>
__global__ __launch_bounds__(256) void mlp_l2_k(
    const u16* __restrict__ hid, const u16* __restrict__ W2h, const u16* __restrict__ W2l,
    const void* __restrict__ b2v, void* __restrict__ out, long obase, long row0,
    int M, const int* __restrict__ mflag)
{
    const int m = *mflag;
    int tid = threadIdx.x, lane = tid & 63, w = tid >> 6;
    int lm = lane & 15, quad = lane >> 4;
    int m0 = blockIdx.x * 64 + w * 16;
    int arow = m0 + lm; if (arow >= M) arow = M - 1;
    const u16* ap = hid + (long)arow * 256;
    const u16* wp = W2h + (long)lm * 256;
    const u16* wl = W2l + (long)lm * 256;
    f32x4 acc = {0.f, 0.f, 0.f, 0.f};
#pragma unroll
    for (int k0 = 0; k0 < 256; k0 += 32) {
        s16x8 a  = *(const s16x8*)(ap + k0 + quad * 8);
        s16x8 bh = *(const s16x8*)(wp + k0 + quad * 8);
        acc = mfma_bf16(a, bh, acc);
        if (m) {
            s16x8 bl = *(const s16x8*)(wl + k0 + quad * 8);
            acc = mfma_bf16(a, bl, acc);
        }
    }
    if (lm < NOUT) {
        float b2 = ld1(b2v, lm, m);
#pragma unroll
        for (int rr = 0; rr < 4; ++rr) {
            int grow = m0 + quad * 4 + rr;
            if (grow < M)
                stout(out, obase + (long)(row0 + grow) * NOUT + lm, acc[rr] + b2, m);
        }
    }
}

// ---------------- tp: wave-per-edge contiguous 640-dot, vectorized ----------------
__global__ __launch_bounds__(256) void tp_k(
    const int* __restrict__ ei, const void* __restrict__ h,
    const u16* __restrict__ PQ, float* __restrict__ tp,
    const int* __restrict__ mflag)
{
    const int m = *mflag;
    int wave = threadIdx.x >> 6, lane = threadIdx.x & 63;
    int e = blockIdx.x * 4 + wave;
    if (e >= NEDGE) return;
    int row = ei[e], col = ei[NEDGE + e];
    const u16* pq = PQ + (long)row * 640;
    ushort4 p0 = *(const ushort4*)(pq + lane * 8);
    ushort4 p1 = *(const ushort4*)(pq + lane * 8 + 4);
    ushort2 p2 = *(const ushort2*)(pq + 512 + lane * 2);
    float acc;
    if (m) {
        const float* hp = (const float*)h + (long)col * 640;
        float4 h0 = *(const float4*)(hp + lane * 8);
        float4 h1 = *(const float4*)(hp + lane * 8 + 4);
        float2 h2 = *(const float2*)(hp + 512 + lane * 2);
        acc = b2f(p0.x) * h0.x + b2f(p0.y) * h0.y + b2f(p0.z) * h0.z + b2f(p0.w) * h0.w
            + b2f(p1.x) * h1.x + b2f(p1.y) * h1.y + b2f(p1.z) * h1.z + b2f(p1.w) * h1.w
            + b2f(p2.x) * h2.x + b2f(p2.y) * h2.y;
    } else {
        const u16* hp = (const u16*)h + (long)col * 640;
        ushort4 h0 = *(const ushort4*)(hp + lane * 8);
        ushort4 h1 = *(const ushort4*)(hp + lane * 8 + 4);
        ushort2 h2 = *(const ushort2*)(hp + 512 + lane * 2);
        acc = b2f(p0.x) * b2f(h0.x) + b2f(p0.y) * b2f(h0.y) + b2f(p0.z) * b2f(h0.z) + b2f(p0.w) * b2f(h0.w)
            + b2f(p1.x) * b2f(h1.x) + b2f(p1.y) * b2f(h1.y) + b2f(p1.z) * b2f(h1.z) + b2f(p1.w) * b2f(h1.w)
            + b2f(p2.x) * b2f(h2.x) + b2f(p2.y) * b2f(h2.y);
    }
#pragma unroll
    for (int off = 32; off > 0; off >>= 1) acc += __shfl_down(acc, off);
    if (lane == 0) tp[e] = acc;
}

// ---------------- r0: thread per (n,i) ----------------
__global__ __launch_bounds__(256) void r0_k(
    const void* __restrict__ h, const float* __restrict__ w_eff,
    void* __restrict__ out, const int* __restrict__ mflag)
{
    const int m = *mflag;
    int t = blockIdx.x * 256 + threadIdx.x;
    if (t >= 150000) return;
    int n = t / 3, i = t - n * 3;
    long base = (long)n * 640 + 256 + i;
    float acc = 0.f;
#pragma unroll 4
    for (int c = 0; c < 128; ++c) acc += w_eff[c] * ld1(h, base + 3L * c, m);
    stout(out, 800000L + t, acc, m);
}

extern "C" void kernel_launch(void* const* d_in, const int* in_sizes, int n_in,
                              void* d_out, int out_size, void* d_ws, size_t ws_size,
                              hipStream_t stream) {
    (void)in_sizes; (void)n_in; (void)out_size; (void)ws_size;
    const void* h      = d_in[0];
    const void* e_fin  = d_in[1];
    const int*  ei     = (const int*)d_in[4];
    const void* Ws_w   = d_in[5];
    const void* Ws_b   = d_in[6];
    const void* Wv     = d_in[7];
    const void* Wcoord = d_in[8];
    const void* W00    = d_in[9];
    const void* W11    = d_in[10];
    const void* aW1    = d_in[11];
    const void* ab1    = d_in[12];
    const void* aW2    = d_in[13];
    const void* ab2    = d_in[14];
    const void* bW1    = d_in[15];
    const void* bb1    = d_in[16];
    const void* bW2    = d_in[17];
    const void* bb2    = d_in[18];

    char* ws = (char*)d_ws;
    int*   mflag = (int*)(ws + 0);
    float* w1tp  = (float*)(ws + 512);
    float* w_eff = (float*)(ws + 2048);
    float* b1p   = (float*)(ws + 3072);
    u16*   W00T  = (u16*)(ws + 4096);       // 131072
    u16*   W11T  = (u16*)(ws + 135168);     // 32768
    u16*   W1eh  = (u16*)(ws + 167936);     // 32768
    u16*   W1el  = (u16*)(ws + 200704);     // 32768
    u16*   W1sh  = (u16*)(ws + 233472);     // 131072
    u16*   W1sl  = (u16*)(ws + 364544);     // 131072
    u16*   W2ah  = (u16*)(ws + 495616);     // 8192
    u16*   W2al  = (u16*)(ws + 503808);     // 8192
    u16*   W2bh  = (u16*)(ws + 512000);     // 8192
    u16*   W2bl  = (u16*)(ws + 520192);     // 8192
    float* tp    = (float*)(ws + 528384);   // 800000
    // shared big region R (64 MB): hidA, then PQ, then hidB chunks
    char*  R     = ws + 1337344;
    u16*   hidA  = (u16*)R;                 // 50000*256*2  = 25.6 MB
    u16*   PQ    = (u16*)R;                 // 50000*640*2  = 64.0 MB
    u16*   hidB  = (u16*)R;                 // 100000*256*2 = 51.2 MB per chunk
    // total ws use: ~65.3 MB

    u16* /*outs*/ _unused = nullptr; (void)_unused;

    detect_k<<<1, 256, 0, stream>>>(h, mflag);
    prep_misc_k<<<418, 256, 0, stream>>>(W00, W11, bW1, Wv, Wcoord, aW2, bW2,
                                         W00T, W11T, W1eh, W1el, w1tp, w_eff,
                                         W2ah, W2al, W2bh, W2bl, mflag);
    prep_w1s_k<<<256, 256, 0, stream>>>(aW1, Ws_w, Ws_b, ab1, W1sh, W1sl, b1p, mflag);

    // ---- atom head (uses R as hidA) ----
    mlp_l1_k<256, false><<<dim3(2, 391), 256, 0, stream>>>(
        h, 640, 0L, W1sh, W1sl, b1p, nullptr, nullptr, nullptr,
        hidA, NNODE, 1, mflag);
    mlp_l2_k<16><<<782, 256, 0, stream>>>(hidA, W2ah, W2al, ab2,
                                          d_out, 0L, 0L, NNODE, mflag);
    // ---- r0 ----
    r0_k<<<586, 256, 0, stream>>>(h, w_eff, d_out, mflag);

    // ---- PQ (overwrites hidA region) ----
    gemm_pq_k<false><<<dim3(2, 391, 1), 256, 0, stream>>>(
        h, 640, 0, W00T, 256, PQ, 640, 1, 0, INV_SQRT_FAN, NNODE, 256, mflag);
    gemm_pq_k<true><<<dim3(1, 391, 3), 256, 0, stream>>>(
        h, 640, 256, W11T, 128, PQ, 640, 3, 256, INV_SQRT_FAN * INV_SQRT3, NNODE, 128, mflag);
    tp_k<<<50000, 256, 0, stream>>>(ei, h, PQ, tp, mflag);

    // ---- bond head, 2 chunks of 100000 edges (hidB overwrites PQ region) ----
    for (int chunk = 0; chunk < 2; ++chunk) {
        long row0 = (long)chunk * 100000;
        mlp_l1_k<64, true><<<dim3(2, 782), 256, 0, stream>>>(
            e_fin, 64, row0, W1eh, W1el, nullptr, bb1, tp, w1tp,
            hidB, 100000, 0, mflag);
        mlp_l2_k<5><<<1563, 256, 0, stream>>>(hidB, W2bh, W2bl, bb2,
                                              d_out, 950000L, row0, 100000, mflag);
    }
}

// Round 4
// 744.838 us; speedup vs baseline: 1.2023x; 1.1289x over previous
//
#include <hip/hip_runtime.h>

typedef unsigned short u16;
typedef float f32x4 __attribute__((ext_vector_type(4)));
typedef float f32x2 __attribute__((ext_vector_type(2)));
typedef short s16x8 __attribute__((ext_vector_type(8)));
typedef __bf16 bf16x8 __attribute__((ext_vector_type(8)));

#define NNODE 50000
#define NEDGE 200000
#define INV_SQRT3 0.57735026918962576f
#define INV_SQRT_FAN 0.0034938562148434216f  /* 1/sqrt(256^2+128^2) */

__device__ inline float b2f(u16 x) {
    unsigned u = ((unsigned)x) << 16;
    return __builtin_bit_cast(float, u);
}
__device__ inline u16 f2b(float f) {
    unsigned u = __builtin_bit_cast(unsigned, f);
    unsigned r = u + 0x7FFFu + ((u >> 16) & 1u);
    return (u16)(r >> 16);
}
__device__ inline float silu(float v) { return v / (1.f + __expf(-v)); }

__device__ inline float ld1(const void* p, long i, int m) {
    return m ? ((const float*)p)[i] : b2f(((const u16*)p)[i]);
}
__device__ inline void stout(void* o, long i, float v, int m) {
    if (m) ((float*)o)[i] = v; else ((u16*)o)[i] = f2b(v);
}

// ---------------- fp8 e4m3fn codec (HW builtin if present, else soft) ----------------
#if defined(__has_builtin)
# if __has_builtin(__builtin_amdgcn_cvt_pk_f32_fp8) && __has_builtin(__builtin_amdgcn_cvt_pk_fp8_f32)
#  define HAVE_FP8 1
# endif
#endif
#ifndef HAVE_FP8
# define HAVE_FP8 0
#endif

__device__ inline int f2e4m3_soft(float f) {
    unsigned u = __builtin_bit_cast(unsigned, f);
    int s = (u >> 24) & 0x80;
    float a = __builtin_fabsf(f);
    if (a >= 464.f) return s | 0x7E;
    if (a < 0.015625f) {
        int q = (int)(a * 512.f + 0.5f);
        return s | q;
    }
    int e = (int)((u >> 23) & 0xFF) - 127;
    unsigned m = u & 0x7FFFFF;
    unsigned mq = (m + 0x80000) >> 20;
    if (mq == 8) { mq = 0; e += 1; }
    if (e > 8) return s | 0x7E;
    return s | ((e + 7) << 3) | (int)mq;
}
__device__ inline float e4m3f_soft(int b) {
    int em = b & 0x7F;
    float v;
    if (em >> 3) {
        unsigned bits = ((unsigned)((em >> 3) + 120) << 23) | ((unsigned)(em & 7) << 20);
        v = __builtin_bit_cast(float, bits);
    } else {
        v = (float)em * 0.001953125f;
    }
    return (b & 0x80) ? -v : v;
}
__device__ inline int enc2(float a, float b) {  // 2 fp8 packed in low 16 bits
#if HAVE_FP8
    return __builtin_amdgcn_cvt_pk_fp8_f32(a, b, 0, false) & 0xFFFF;
#else
    return f2e4m3_soft(a) | (f2e4m3_soft(b) << 8);
#endif
}
__device__ inline unsigned char enc1(float a) { return (unsigned char)(enc2(a, a) & 0xFF); }

__device__ inline float dot8(unsigned p, unsigned x, float acc) {
#if HAVE_FP8
    f32x2 p0 = __builtin_amdgcn_cvt_pk_f32_fp8((int)p, false);
    f32x2 p1 = __builtin_amdgcn_cvt_pk_f32_fp8((int)p, true);
    f32x2 x0 = __builtin_amdgcn_cvt_pk_f32_fp8((int)x, false);
    f32x2 x1 = __builtin_amdgcn_cvt_pk_f32_fp8((int)x, true);
    return acc + p0.x * x0.x + p0.y * x0.y + p1.x * x1.x + p1.y * x1.y;
#else
    float r = acc;
#pragma unroll
    for (int i = 0; i < 4; ++i)
        r += e4m3f_soft((p >> (8 * i)) & 0xFF) * e4m3f_soft((x >> (8 * i)) & 0xFF);
    return r;
#endif
}
__device__ inline float dot2(unsigned p, unsigned x, float acc) {
#if HAVE_FP8
    f32x2 p0 = __builtin_amdgcn_cvt_pk_f32_fp8((int)p, false);
    f32x2 x0 = __builtin_amdgcn_cvt_pk_f32_fp8((int)x, false);
    return acc + p0.x * x0.x + p0.y * x0.y;
#else
    return acc + e4m3f_soft(p & 0xFF) * e4m3f_soft(x & 0xFF)
               + e4m3f_soft((p >> 8) & 0xFF) * e4m3f_soft((x >> 8) & 0xFF);
#endif
}

// MFMA wrapper tolerant to either builtin signature.
template <typename V>
__device__ auto mfma_sel(V a, V b, f32x4 c, int)
    -> decltype(__builtin_amdgcn_mfma_f32_16x16x32_bf16(a, b, c, 0, 0, 0)) {
    return __builtin_amdgcn_mfma_f32_16x16x32_bf16(a, b, c, 0, 0, 0);
}
template <typename V>
__device__ f32x4 mfma_sel(V a, V b, f32x4 c, long) {
    bf16x8 aa = __builtin_bit_cast(bf16x8, a);
    bf16x8 bb = __builtin_bit_cast(bf16x8, b);
    return __builtin_amdgcn_mfma_f32_16x16x32_bf16(aa, bb, c, 0, 0, 0);
}
__device__ inline f32x4 mfma_bf16(s16x8 a, s16x8 b, f32x4 c) {
    return mfma_sel(a, b, c, 0);
}

// ---------------- detect input storage dtype ----------------
__global__ __launch_bounds__(256) void detect_k(const void* __restrict__ h, int* __restrict__ flag) {
    int t = threadIdx.x;
    u16 w = ((const u16*)h)[2 * t];
    int tb = (w >> 8) & 0x7F;
    bool pl = (tb >= 0x38 && tb <= 0x41);
    unsigned long long b = __ballot(pl);
    __shared__ int cnt[4];
    if ((t & 63) == 0) cnt[t >> 6] = __popcll(b);
    __syncthreads();
    if (t == 0) {
        int s = cnt[0] + cnt[1] + cnt[2] + cnt[3];
        flag[0] = (s < 128) ? 1 : 0;  // 1 = f32 storage
    }
}

// ---------------- prep: transposes / splits / w_eff / Bq ----------------
__global__ __launch_bounds__(256) void prep_misc_k(
    const void* __restrict__ W00, const void* __restrict__ W11,
    const void* __restrict__ bW1, const void* __restrict__ Wv,
    const void* __restrict__ Wcoord, const void* __restrict__ aW2,
    const void* __restrict__ bW2,
    u16* __restrict__ W00T, u16* __restrict__ W1eh, u16* __restrict__ W1el,
    float* __restrict__ w1tp, float* __restrict__ w_eff,
    u16* __restrict__ W2ah, u16* __restrict__ W2al,
    u16* __restrict__ W2bh, u16* __restrict__ W2bl,
    u16* __restrict__ Bq, const int* __restrict__ mflag)
{
    const int m = *mflag;
    int u = blockIdx.x * 256 + threadIdx.x;
    if (u < 65536) {                 // W00T[j][i] = W00[i][j]
        int j = u >> 8, i = u & 255;
        W00T[u] = f2b(ld1(W00, (long)i * 256 + j, m));
    } else if (u < 81920) {          // bond W1 split
        int v = u - 65536; int hd = v >> 6, k = v & 63;
        float x = ld1(bW1, (long)hd * 65 + 1 + k, m);
        u16 hi = f2b(x);
        W1eh[v] = hi;
        W1el[v] = f2b(x - b2f(hi));
    } else if (u < 82176) {          // w1tp
        int hd = u - 81920;
        w1tp[hd] = ld1(bW1, (long)hd * 65, m);
    } else if (u < 82304) {          // w_eff
        int c = u - 82176;
        float acc = 0.f;
        for (int d = 0; d < 128; ++d)
            acc += ld1(Wcoord, d, m) * ld1(Wv, (long)d * 128 + c, m);
        w_eff[c] = acc;
    } else if (u < 86400) {          // atom W2 split (16x256)
        int v = u - 82304;
        float x = ld1(aW2, v, m);
        u16 hi = f2b(x);
        W2ah[v] = hi;
        W2al[v] = f2b(x - b2f(hi));
    } else if (u < 90496) {          // bond W2 padded 16x256, split
        int v = u - 86400; int o = v >> 8, k = v & 255;
        float x = (o < 5) ? ld1(bW2, (long)o * 256 + k, m) : 0.f;
        u16 hi = f2b(x);
        W2bh[v] = hi;
        W2bl[v] = f2b(x - b2f(hi));
    } else if (u < 237952) {         // Bq[j][k] 384x384: (j%3==k%3) ? W11[k/3][j/3] : 0
        int v = u - 90496;
        int j = v / 384, k = v - j * 384;
        float x = 0.f;
        if (j % 3 == k % 3) x = ld1(W11, (long)(k / 3) * 128 + (j / 3), m);
        Bq[v] = f2b(x);
    }
}

// W1s = atom_W1 @ Ws_w, split bf16; b1p = atom_W1@Ws_b + atom_b1
__global__ __launch_bounds__(256) void prep_w1s_k(
    const void* __restrict__ aW1, const void* __restrict__ Wsw,
    const void* __restrict__ Wsb, const void* __restrict__ ab1,
    u16* __restrict__ W1sh, u16* __restrict__ W1sl, float* __restrict__ b1p,
    const int* __restrict__ mflag)
{
    const int m = *mflag;
    int hd = blockIdx.x, s = threadIdx.x;
    float acc = 0.f;
    for (int j = 0; j < 256; ++j)
        acc += ld1(aW1, (long)hd * 256 + j, m) * ld1(Wsw, (long)j * 256 + s, m);
    u16 hi = f2b(acc);
    W1sh[hd * 256 + s] = hi;
    W1sl[hd * 256 + s] = f2b(acc - b2f(hi));
    if (s == 0) {
        float b = ld1(ab1, hd, m);
        for (int j = 0; j < 256; ++j)
            b += ld1(aW1, (long)hd * 256 + j, m) * ld1(Wsb, j, m);
        b1p[hd] = b;
    }
}

// ---------------- x8: fp8 copy of h ----------------
__global__ __launch_bounds__(256) void x8_k(const void* __restrict__ h,
                                            unsigned char* __restrict__ X8,
                                            const int* __restrict__ mflag)
{
    const int m = *mflag;
    long t = (long)blockIdx.x * 256 + threadIdx.x;   // 4,000,000 threads x 8 elems
    long base = t * 8;
    float f[8];
    if (m) {
        float4 a = *(const float4*)((const float*)h + base);
        float4 b = *(const float4*)((const float*)h + base + 4);
        f[0] = a.x; f[1] = a.y; f[2] = a.z; f[3] = a.w;
        f[4] = b.x; f[5] = b.y; f[6] = b.z; f[7] = b.w;
    } else {
        ushort4 a = *(const ushort4*)((const u16*)h + base);
        ushort4 b = *(const ushort4*)((const u16*)h + base + 4);
        f[0] = b2f(a.x); f[1] = b2f(a.y); f[2] = b2f(a.z); f[3] = b2f(a.w);
        f[4] = b2f(b.x); f[5] = b2f(b.y); f[6] = b2f(b.z); f[7] = b2f(b.w);
    }
    unsigned w0 = (unsigned)enc2(f[0], f[1]) | ((unsigned)enc2(f[2], f[3]) << 16);
    unsigned w1 = (unsigned)enc2(f[4], f[5]) | ((unsigned)enc2(f[6], f[7]) << 16);
    *(uint2*)(X8 + base) = make_uint2(w0, w1);
}

// ---------------- GEMM -> fp8 PQ8: PQ8[row*640 + coff + col] = fp8(scale * A@Bt^T) ----------------
__global__ __launch_bounds__(256) void gemm8_k(
    const void* __restrict__ A, int lda, int aoff,
    const u16* __restrict__ Bt, int ldb,
    unsigned char* __restrict__ PQ8, int coff,
    float scale, int M, int K, const int* __restrict__ mflag)
{
    const int m = *mflag;
    __shared__ __align__(16) u16 As[128][40];
    __shared__ __align__(16) u16 Bs[128][40];
    int tid = threadIdx.x;
    int lane = tid & 63, wave = tid >> 6;
    int wm = (wave & 1) * 64, wn = (wave >> 1) * 64;
    int lm = lane & 15, quad = lane >> 4;
    int bm0 = blockIdx.y * 128, bn0 = blockIdx.x * 128;
    f32x4 acc[4][4] = {};
    int r = tid >> 2, c = tid & 3;
    for (int k0 = 0; k0 < K; k0 += 32) {
#pragma unroll
        for (int p = 0; p < 2; ++p) {
            int row = p * 64 + r;
            int grow = bm0 + row;
            u16 tmp[8];
            if (grow < M) {
                long base = (long)grow * lda + aoff + k0 + c * 8;
                if (m) {
                    float4 a0 = *(const float4*)((const float*)A + base);
                    float4 a1 = *(const float4*)((const float*)A + base + 4);
                    tmp[0] = f2b(a0.x); tmp[1] = f2b(a0.y); tmp[2] = f2b(a0.z); tmp[3] = f2b(a0.w);
                    tmp[4] = f2b(a1.x); tmp[5] = f2b(a1.y); tmp[6] = f2b(a1.z); tmp[7] = f2b(a1.w);
                } else {
                    *(ushort4*)&tmp[0] = *(const ushort4*)((const u16*)A + base);
                    *(ushort4*)&tmp[4] = *(const ushort4*)((const u16*)A + base + 4);
                }
            } else {
#pragma unroll
                for (int j = 0; j < 8; ++j) tmp[j] = 0;
            }
            *(ushort4*)&As[row][c * 8]     = *(ushort4*)&tmp[0];
            *(ushort4*)&As[row][c * 8 + 4] = *(ushort4*)&tmp[4];
            long bb = (long)(bn0 + row) * ldb + k0 + c * 8;
            *(ushort4*)&Bs[row][c * 8]     = *(const ushort4*)(Bt + bb);
            *(ushort4*)&Bs[row][c * 8 + 4] = *(const ushort4*)(Bt + bb + 4);
        }
        __syncthreads();
        s16x8 af[4], bfr[4];
#pragma unroll
        for (int t = 0; t < 4; ++t) {
            af[t]  = *(const s16x8*)&As[wm + t * 16 + lm][quad * 8];
            bfr[t] = *(const s16x8*)&Bs[wn + t * 16 + lm][quad * 8];
        }
#pragma unroll
        for (int i = 0; i < 4; ++i)
#pragma unroll
            for (int j = 0; j < 4; ++j)
                acc[i][j] = mfma_bf16(af[i], bfr[j], acc[i][j]);
        __syncthreads();
    }
#pragma unroll
    for (int j = 0; j < 4; ++j) {
        int col = bn0 + wn + j * 16 + lm;
#pragma unroll
        for (int i = 0; i < 4; ++i)
#pragma unroll
            for (int rr = 0; rr < 4; ++rr) {
                int grow = bm0 + wm + i * 16 + quad * 4 + rr;
                if (grow < M)
                    PQ8[(long)grow * 640 + coff + col] = enc1(scale * acc[i][j][rr]);
            }
    }
}

// ---------------- MLP layer1: hid = silu(A@W1^T [+tp*w1tp] + b1), bf16 out ----------------
template <int KDIM, bool BOND>
__global__ __launch_bounds__(256) void mlp_l1_k(
    const void* __restrict__ A, int lda, long row0,
    const u16* __restrict__ Bh, const u16* __restrict__ Bl,
    const float* __restrict__ b1p, const void* __restrict__ b1v,
    const float* __restrict__ tp, const float* __restrict__ w1tp,
    u16* __restrict__ hid, int M, const int* __restrict__ mflag)
{
    const int m = *mflag;
    __shared__ __align__(16) u16 Ah[128][40], Al[128][40];
    __shared__ __align__(16) u16 Bsh[128][40], Bsl[128][40];
    int tid = threadIdx.x;
    int lane = tid & 63, wave = tid >> 6;
    int wm = (wave & 1) * 64, wn = (wave >> 1) * 64;
    int lm = lane & 15, quad = lane >> 4;
    int bm0 = blockIdx.y * 128, bn0 = blockIdx.x * 128;
    f32x4 acc[4][4] = {};
    int r = tid >> 2, c = tid & 3;
    for (int k0 = 0; k0 < KDIM; k0 += 32) {
#pragma unroll
        for (int p = 0; p < 2; ++p) {
            int row = p * 64 + r;
            int grow = bm0 + row;
            u16 th[8], tl[8];
            if (grow < M) {
                long base = (long)(row0 + grow) * lda + k0 + c * 8;
                if (m) {
                    float4 a0 = *(const float4*)((const float*)A + base);
                    float4 a1 = *(const float4*)((const float*)A + base + 4);
                    float v[8] = {a0.x, a0.y, a0.z, a0.w, a1.x, a1.y, a1.z, a1.w};
#pragma unroll
                    for (int j = 0; j < 8; ++j) { th[j] = f2b(v[j]); tl[j] = f2b(v[j] - b2f(th[j])); }
                } else {
                    *(ushort4*)&th[0] = *(const ushort4*)((const u16*)A + base);
                    *(ushort4*)&th[4] = *(const ushort4*)((const u16*)A + base + 4);
                }
            } else {
#pragma unroll
                for (int j = 0; j < 8; ++j) { th[j] = 0; tl[j] = 0; }
            }
            *(ushort4*)&Ah[row][c * 8]     = *(ushort4*)&th[0];
            *(ushort4*)&Ah[row][c * 8 + 4] = *(ushort4*)&th[4];
            if (m) {
                *(ushort4*)&Al[row][c * 8]     = *(ushort4*)&tl[0];
                *(ushort4*)&Al[row][c * 8 + 4] = *(ushort4*)&tl[4];
            }
            long bb = (long)(bn0 + row) * KDIM + k0 + c * 8;
            *(ushort4*)&Bsh[row][c * 8]     = *(const ushort4*)(Bh + bb);
            *(ushort4*)&Bsh[row][c * 8 + 4] = *(const ushort4*)(Bh + bb + 4);
            if (m) {
                *(ushort4*)&Bsl[row][c * 8]     = *(const ushort4*)(Bl + bb);
                *(ushort4*)&Bsl[row][c * 8 + 4] = *(const ushort4*)(Bl + bb + 4);
            }
        }
        __syncthreads();
        s16x8 af[4], bfh[4];
#pragma unroll
        for (int t = 0; t < 4; ++t) {
            af[t]  = *(const s16x8*)&Ah[wm + t * 16 + lm][quad * 8];
            bfh[t] = *(const s16x8*)&Bsh[wn + t * 16 + lm][quad * 8];
        }
#pragma unroll
        for (int i = 0; i < 4; ++i)
#pragma unroll
            for (int j = 0; j < 4; ++j)
                acc[i][j] = mfma_bf16(af[i], bfh[j], acc[i][j]);
        if (m) {
#pragma unroll
            for (int j = 0; j < 4; ++j) {
                s16x8 bl = *(const s16x8*)&Bsl[wn + j * 16 + lm][quad * 8];
#pragma unroll
                for (int i = 0; i < 4; ++i)
                    acc[i][j] = mfma_bf16(af[i], bl, acc[i][j]);
            }
#pragma unroll
            for (int i = 0; i < 4; ++i) {
                s16x8 al = *(const s16x8*)&Al[wm + i * 16 + lm][quad * 8];
#pragma unroll
                for (int j = 0; j < 4; ++j) {
                    s16x8 bh = *(const s16x8*)&Bsh[wn + j * 16 + lm][quad * 8];
                    acc[i][j] = mfma_bf16(al, bh, acc[i][j]);
                }
            }
        }
        __syncthreads();
    }
#pragma unroll
    for (int j = 0; j < 4; ++j) {
        int col = bn0 + wn + j * 16 + lm;
        float bb = BOND ? ld1(b1v, col, m) : b1p[col];
        float wtp = BOND ? w1tp[col] : 0.f;
#pragma unroll
        for (int i = 0; i < 4; ++i)
#pragma unroll
            for (int rr = 0; rr < 4; ++rr) {
                int grow = bm0 + wm + i * 16 + quad * 4 + rr;
                if (grow < M) {
                    float v = acc[i][j][rr] + bb;
                    if (BOND) v += tp[row0 + grow] * wtp;
                    hid[(long)grow * 256 + col] = f2b(silu(v));
                }
            }
    }
}

// ---------------- MLP layer2: wave per 16-row tile, no LDS ----------------
template <int NOUT>
__global__ __launch_bounds__(256) void mlp_l2_k(
    const u16* __restrict__ hid, const u16* __restrict__ W2h, const u16* __restrict__ W2l,
    const void* __restrict__ b2v, void* __restrict__ out, long obase, long row0,
    int M, const int* __restrict__ mflag)
{
    const int m = *mflag;
    int tid = threadIdx.x, lane = tid & 63, w = tid >> 6;
    int lm = lane & 15, quad = lane >> 4;
    int m0 = blockIdx.x * 64 + w * 16;
    int arow = m0 + lm; if (arow >= M) arow = M - 1;
    const u16* ap = hid + (long)arow * 256;
    const u16* wp = W2h + (long)lm * 256;
    const u16* wl = W2l + (long)lm * 256;
    f32x4 acc = {0.f, 0.f, 0.f, 0.f};
#pragma unroll
    for (int k0 = 0; k0 < 256; k0 += 32) {
        s16x8 a  = *(const s16x8*)(ap + k0 + quad * 8);
        s16x8 bh = *(const s16x8*)(wp + k0 + quad * 8);
        acc = mfma_bf16(a, bh, acc);
        if (m) {
            s16x8 bl = *(const s16x8*)(wl + k0 + quad * 8);
            acc = mfma_bf16(a, bl, acc);
        }
    }
    if (lm < NOUT) {
        float b2 = ld1(b2v, lm, m);
#pragma unroll
        for (int rr = 0; rr < 4; ++rr) {
            int grow = m0 + quad * 4 + rr;
            if (grow < M)
                stout(out, obase + (long)(row0 + grow) * NOUT + lm, acc[rr] + b2, m);
        }
    }
}

// ---------------- tp: wave-per-edge fp8 640-dot ----------------
__global__ __launch_bounds__(256) void tp_k(
    const int* __restrict__ ei, const unsigned char* __restrict__ PQ8,
    const unsigned char* __restrict__ X8, float* __restrict__ tp)
{
    int wave = threadIdx.x >> 6, lane = threadIdx.x & 63;
    int e = blockIdx.x * 4 + wave;
    if (e >= NEDGE) return;
    int row = ei[e], col = ei[NEDGE + e];
    const unsigned char* pq = PQ8 + (long)row * 640;
    const unsigned char* xp = X8 + (long)col * 640;
    uint2 pw = *(const uint2*)(pq + lane * 8);
    uint2 xw = *(const uint2*)(xp + lane * 8);
    unsigned pt = *(const unsigned short*)(pq + 512 + lane * 2);
    unsigned xt = *(const unsigned short*)(xp + 512 + lane * 2);
    float acc = 0.f;
    acc = dot8(pw.x, xw.x, acc);
    acc = dot8(pw.y, xw.y, acc);
    acc = dot2(pt, xt, acc);
#pragma unroll
    for (int off = 32; off > 0; off >>= 1) acc += __shfl_down(acc, off);
    if (lane == 0) tp[e] = acc * 0.0625f;   // undo x16 PQ pre-scale
}

// ---------------- r0: 32 lanes per node, vector loads + shuffle reduce ----------------
__global__ __launch_bounds__(256) void r0_k(
    const void* __restrict__ h, const float* __restrict__ w_eff,
    void* __restrict__ out, const int* __restrict__ mflag)
{
    const int m = *mflag;
    int tid = threadIdx.x, lane = tid & 63, wave = tid >> 6;
    int half = lane >> 5, l32 = lane & 31;
    int node = blockIdx.x * 8 + wave * 2 + half;   // 6250 blocks x 8 nodes
    if (node >= NNODE) return;
    long base = (long)node * 640 + 256 + l32 * 12;
    float x[12];
    if (m) {
        float4 a = *(const float4*)((const float*)h + base);
        float4 b = *(const float4*)((const float*)h + base + 4);
        float4 cc = *(const float4*)((const float*)h + base + 8);
        x[0]=a.x; x[1]=a.y; x[2]=a.z; x[3]=a.w;
        x[4]=b.x; x[5]=b.y; x[6]=b.z; x[7]=b.w;
        x[8]=cc.x; x[9]=cc.y; x[10]=cc.z; x[11]=cc.w;
    } else {
        ushort4 a = *(const ushort4*)((const u16*)h + base);
        ushort4 b = *(const ushort4*)((const u16*)h + base + 4);
        ushort4 cc = *(const ushort4*)((const u16*)h + base + 8);
        x[0]=b2f(a.x); x[1]=b2f(a.y); x[2]=b2f(a.z); x[3]=b2f(a.w);
        x[4]=b2f(b.x); x[5]=b2f(b.y); x[6]=b2f(b.z); x[7]=b2f(b.w);
        x[8]=b2f(cc.x); x[9]=b2f(cc.y); x[10]=b2f(cc.z); x[11]=b2f(cc.w);
    }
    float4 wv = *(const float4*)(w_eff + l32 * 4);
    float s0 = x[0]*wv.x + x[3]*wv.y + x[6]*wv.z + x[9]*wv.w;
    float s1 = x[1]*wv.x + x[4]*wv.y + x[7]*wv.z + x[10]*wv.w;
    float s2 = x[2]*wv.x + x[5]*wv.y + x[8]*wv.z + x[11]*wv.w;
#pragma unroll
    for (int off = 16; off > 0; off >>= 1) {
        s0 += __shfl_down(s0, off, 32);
        s1 += __shfl_down(s1, off, 32);
        s2 += __shfl_down(s2, off, 32);
    }
    if (l32 == 0) {
        stout(out, 800000L + (long)node * 3 + 0, s0, m);
        stout(out, 800000L + (long)node * 3 + 1, s1, m);
        stout(out, 800000L + (long)node * 3 + 2, s2, m);
    }
}

extern "C" void kernel_launch(void* const* d_in, const int* in_sizes, int n_in,
                              void* d_out, int out_size, void* d_ws, size_t ws_size,
                              hipStream_t stream) {
    (void)in_sizes; (void)n_in; (void)out_size; (void)ws_size;
    const void* h      = d_in[0];
    const void* e_fin  = d_in[1];
    const int*  ei     = (const int*)d_in[4];
    const void* Ws_w   = d_in[5];
    const void* Ws_b   = d_in[6];
    const void* Wv     = d_in[7];
    const void* Wcoord = d_in[8];
    const void* W00    = d_in[9];
    const void* W11    = d_in[10];
    const void* aW1    = d_in[11];
    const void* ab1    = d_in[12];
    const void* aW2    = d_in[13];
    const void* ab2    = d_in[14];
    const void* bW1    = d_in[15];
    const void* bb1    = d_in[16];
    const void* bW2    = d_in[17];
    const void* bb2    = d_in[18];

    char* ws = (char*)d_ws;
    int*   mflag = (int*)(ws + 0);
    float* w1tp  = (float*)(ws + 512);
    float* w_eff = (float*)(ws + 2048);
    float* b1p   = (float*)(ws + 3072);
    u16*   W00T  = (u16*)(ws + 4096);       // 131072 -> 135168
    u16*   W1eh  = (u16*)(ws + 135168);     // 32768  -> 167936
    u16*   W1el  = (u16*)(ws + 167936);     // 32768  -> 200704
    u16*   W1sh  = (u16*)(ws + 200704);     // 131072 -> 331776
    u16*   W1sl  = (u16*)(ws + 331776);     // 131072 -> 462848
    u16*   W2ah  = (u16*)(ws + 462848);     // 8192   -> 471040
    u16*   W2al  = (u16*)(ws + 471040);     // 8192   -> 479232
    u16*   W2bh  = (u16*)(ws + 479232);     // 8192   -> 487424
    u16*   W2bl  = (u16*)(ws + 487424);     // 8192   -> 495616
    u16*   Bq    = (u16*)(ws + 495616);     // 294912 -> 790528
    float* tp    = (float*)(ws + 790528);   // 800000 -> 1590528
    char*  R     = ws + 1591296;            // 64 MB shared region
    u16*           hidA = (u16*)R;                          // 25.6 MB
    unsigned char* PQ8  = (unsigned char*)R;                // 32 MB
    unsigned char* X8   = (unsigned char*)(R + 33554432);   // 32 MB
    u16*           hidB = (u16*)R;                          // 51.2 MB

    detect_k<<<1, 256, 0, stream>>>(h, mflag);
    prep_misc_k<<<930, 256, 0, stream>>>(W00, W11, bW1, Wv, Wcoord, aW2, bW2,
                                         W00T, W1eh, W1el, w1tp, w_eff,
                                         W2ah, W2al, W2bh, W2bl, Bq, mflag);
    prep_w1s_k<<<256, 256, 0, stream>>>(aW1, Ws_w, Ws_b, ab1, W1sh, W1sl, b1p, mflag);

    // ---- atom head (R as hidA) ----
    mlp_l1_k<256, false><<<dim3(2, 391), 256, 0, stream>>>(
        h, 640, 0L, W1sh, W1sl, b1p, nullptr, nullptr, nullptr, hidA, NNODE, mflag);
    mlp_l2_k<16><<<782, 256, 0, stream>>>(hidA, W2ah, W2al, ab2,
                                          d_out, 0L, 0L, NNODE, mflag);
    // ---- r0 ----
    r0_k<<<6250, 256, 0, stream>>>(h, w_eff, d_out, mflag);

    // ---- PQ8 (overwrites hidA) + X8 ----
    gemm8_k<<<dim3(2, 391), 256, 0, stream>>>(
        h, 640, 0, W00T, 256, PQ8, 0, 16.f * INV_SQRT_FAN, NNODE, 256, mflag);
    gemm8_k<<<dim3(3, 391), 256, 0, stream>>>(
        h, 640, 256, Bq, 384, PQ8, 256, 16.f * INV_SQRT_FAN * INV_SQRT3, NNODE, 384, mflag);
    x8_k<<<15625, 256, 0, stream>>>(h, X8, mflag);
    tp_k<<<50000, 256, 0, stream>>>(ei, PQ8, X8, tp);

    // ---- bond head, 2 chunks of 100000 (hidB overwrites PQ8/X8) ----
    for (int chunk = 0; chunk < 2; ++chunk) {
        long row0 = (long)chunk * 100000;
        mlp_l1_k<64, true><<<dim3(2, 782), 256, 0, stream>>>(
            e_fin, 64, row0, W1eh, W1el, nullptr, bb1, tp, w1tp, hidB, 100000, mflag);
        mlp_l2_k<5><<<1563, 256, 0, stream>>>(hidB, W2bh, W2bl, bb2,
                                              d_out, 950000L, row0, 100000, mflag);
    }
}

// Round 5
// 595.501 us; speedup vs baseline: 1.5038x; 1.2508x over previous
//
#include <hip/hip_runtime.h>

typedef unsigned short u16;
typedef float f32x4 __attribute__((ext_vector_type(4)));
typedef float f32x2 __attribute__((ext_vector_type(2)));
typedef short s16x8 __attribute__((ext_vector_type(8)));
typedef __bf16 bf16x8 __attribute__((ext_vector_type(8)));

#define NNODE 50000
#define NEDGE 200000
#define INV_SQRT3 0.57735026918962576f
#define INV_SQRT_FAN 0.0034938562148434216f  /* 1/sqrt(256^2+128^2) */

__device__ inline float b2f(u16 x) {
    unsigned u = ((unsigned)x) << 16;
    return __builtin_bit_cast(float, u);
}
__device__ inline u16 f2b(float f) {
    unsigned u = __builtin_bit_cast(unsigned, f);
    unsigned r = u + 0x7FFFu + ((u >> 16) & 1u);
    return (u16)(r >> 16);
}
__device__ inline float silu(float v) { return v / (1.f + __expf(-v)); }

__device__ inline float ld1(const void* p, long i, int m) {
    return m ? ((const float*)p)[i] : b2f(((const u16*)p)[i]);
}
__device__ inline void stout(void* o, long i, float v, int m) {
    if (m) ((float*)o)[i] = v; else ((u16*)o)[i] = f2b(v);
}

// ---------------- fp8 e4m3fn codec (HW builtin if present, else soft) ----------------
#if defined(__has_builtin)
# if __has_builtin(__builtin_amdgcn_cvt_pk_f32_fp8) && __has_builtin(__builtin_amdgcn_cvt_pk_fp8_f32)
#  define HAVE_FP8 1
# endif
#endif
#ifndef HAVE_FP8
# define HAVE_FP8 0
#endif

__device__ inline int f2e4m3_soft(float f) {
    unsigned u = __builtin_bit_cast(unsigned, f);
    int s = (u >> 24) & 0x80;
    float a = __builtin_fabsf(f);
    if (a >= 464.f) return s | 0x7E;
    if (a < 0.015625f) {
        int q = (int)(a * 512.f + 0.5f);
        return s | q;
    }
    int e = (int)((u >> 23) & 0xFF) - 127;
    unsigned m = u & 0x7FFFFF;
    unsigned mq = (m + 0x80000) >> 20;
    if (mq == 8) { mq = 0; e += 1; }
    if (e > 8) return s | 0x7E;
    return s | ((e + 7) << 3) | (int)mq;
}
__device__ inline float e4m3f_soft(int b) {
    int em = b & 0x7F;
    float v;
    if (em >> 3) {
        unsigned bits = ((unsigned)((em >> 3) + 120) << 23) | ((unsigned)(em & 7) << 20);
        v = __builtin_bit_cast(float, bits);
    } else {
        v = (float)em * 0.001953125f;
    }
    return (b & 0x80) ? -v : v;
}
__device__ inline int enc2(float a, float b) {
#if HAVE_FP8
    return __builtin_amdgcn_cvt_pk_fp8_f32(a, b, 0, false) & 0xFFFF;
#else
    return f2e4m3_soft(a) | (f2e4m3_soft(b) << 8);
#endif
}
__device__ inline unsigned char enc1(float a) { return (unsigned char)(enc2(a, a) & 0xFF); }

__device__ inline float dot8(unsigned p, unsigned x, float acc) {
#if HAVE_FP8
    f32x2 p0 = __builtin_amdgcn_cvt_pk_f32_fp8((int)p, false);
    f32x2 p1 = __builtin_amdgcn_cvt_pk_f32_fp8((int)p, true);
    f32x2 x0 = __builtin_amdgcn_cvt_pk_f32_fp8((int)x, false);
    f32x2 x1 = __builtin_amdgcn_cvt_pk_f32_fp8((int)x, true);
    return acc + p0.x * x0.x + p0.y * x0.y + p1.x * x1.x + p1.y * x1.y;
#else
    float r = acc;
#pragma unroll
    for (int i = 0; i < 4; ++i)
        r += e4m3f_soft((p >> (8 * i)) & 0xFF) * e4m3f_soft((x >> (8 * i)) & 0xFF);
    return r;
#endif
}
__device__ inline float dot2(unsigned p, unsigned x, float acc) {
#if HAVE_FP8
    f32x2 p0 = __builtin_amdgcn_cvt_pk_f32_fp8((int)p, false);
    f32x2 x0 = __builtin_amdgcn_cvt_pk_f32_fp8((int)x, false);
    return acc + p0.x * x0.x + p0.y * x0.y;
#else
    return acc + e4m3f_soft(p & 0xFF) * e4m3f_soft(x & 0xFF)
               + e4m3f_soft((p >> 8) & 0xFF) * e4m3f_soft((x >> 8) & 0xFF);
#endif
}

// MFMA wrapper tolerant to either builtin signature.
template <typename V>
__device__ auto mfma_sel(V a, V b, f32x4 c, int)
    -> decltype(__builtin_amdgcn_mfma_f32_16x16x32_bf16(a, b, c, 0, 0, 0)) {
    return __builtin_amdgcn_mfma_f32_16x16x32_bf16(a, b, c, 0, 0, 0);
}
template <typename V>
__device__ f32x4 mfma_sel(V a, V b, f32x4 c, long) {
    bf16x8 aa = __builtin_bit_cast(bf16x8, a);
    bf16x8 bb = __builtin_bit_cast(bf16x8, b);
    return __builtin_amdgcn_mfma_f32_16x16x32_bf16(aa, bb, c, 0, 0, 0);
}
__device__ inline f32x4 mfma_bf16(s16x8 a, s16x8 b, f32x4 c) {
    return mfma_sel(a, b, c, 0);
}

// ---------------- detect input storage dtype ----------------
__global__ __launch_bounds__(256) void detect_k(const void* __restrict__ h, int* __restrict__ flag) {
    int t = threadIdx.x;
    u16 w = ((const u16*)h)[2 * t];
    int tb = (w >> 8) & 0x7F;
    bool pl = (tb >= 0x38 && tb <= 0x41);
    unsigned long long b = __ballot(pl);
    __shared__ int cnt[4];
    if ((t & 63) == 0) cnt[t >> 6] = __popcll(b);
    __syncthreads();
    if (t == 0) {
        int s = cnt[0] + cnt[1] + cnt[2] + cnt[3];
        flag[0] = (s < 128) ? 1 : 0;  // 1 = f32 storage
    }
}

// ---------------- prep: transposes / w_eff / Bq (no hi/lo splits) ----------------
__global__ __launch_bounds__(256) void prep_misc_k(
    const void* __restrict__ W00, const void* __restrict__ W11,
    const void* __restrict__ bW1, const void* __restrict__ Wv,
    const void* __restrict__ Wcoord, const void* __restrict__ aW2,
    const void* __restrict__ bW2,
    u16* __restrict__ W00T, u16* __restrict__ W1eh,
    float* __restrict__ w1tp, float* __restrict__ w_eff,
    u16* __restrict__ W2ah, u16* __restrict__ W2bh,
    u16* __restrict__ Bq, const int* __restrict__ mflag)
{
    const int m = *mflag;
    int u = blockIdx.x * 256 + threadIdx.x;
    if (u < 65536) {                 // W00T[j][i] = W00[i][j]
        int j = u >> 8, i = u & 255;
        W00T[u] = f2b(ld1(W00, (long)i * 256 + j, m));
    } else if (u < 81920) {          // bond W1 (k-major, drop tp column)
        int v = u - 65536; int hd = v >> 6, k = v & 63;
        W1eh[v] = f2b(ld1(bW1, (long)hd * 65 + 1 + k, m));
    } else if (u < 82176) {          // w1tp
        int hd = u - 81920;
        w1tp[hd] = ld1(bW1, (long)hd * 65, m);
    } else if (u < 82304) {          // w_eff
        int c = u - 82176;
        float acc = 0.f;
        for (int d = 0; d < 128; ++d)
            acc += ld1(Wcoord, d, m) * ld1(Wv, (long)d * 128 + c, m);
        w_eff[c] = acc;
    } else if (u < 86400) {          // atom W2 (16x256)
        int v = u - 82304;
        W2ah[v] = f2b(ld1(aW2, v, m));
    } else if (u < 90496) {          // bond W2 padded 16x256
        int v = u - 86400; int o = v >> 8, k = v & 255;
        float x = (o < 5) ? ld1(bW2, (long)o * 256 + k, m) : 0.f;
        W2bh[v] = f2b(x);
    } else if (u < 237952) {         // Bq[j][k] 384x384: (j%3==k%3) ? W11[k/3][j/3] : 0
        int v = u - 90496;
        int j = v / 384, k = v - j * 384;
        float x = 0.f;
        if (j % 3 == k % 3) x = ld1(W11, (long)(k / 3) * 128 + (j / 3), m);
        Bq[v] = f2b(x);
    }
}

// W1s = atom_W1 @ Ws_w; b1p = atom_W1@Ws_b + atom_b1
__global__ __launch_bounds__(256) void prep_w1s_k(
    const void* __restrict__ aW1, const void* __restrict__ Wsw,
    const void* __restrict__ Wsb, const void* __restrict__ ab1,
    u16* __restrict__ W1sh, float* __restrict__ b1p,
    const int* __restrict__ mflag)
{
    const int m = *mflag;
    int hd = blockIdx.x, s = threadIdx.x;
    float acc = 0.f;
    for (int j = 0; j < 256; ++j)
        acc += ld1(aW1, (long)hd * 256 + j, m) * ld1(Wsw, (long)j * 256 + s, m);
    W1sh[hd * 256 + s] = f2b(acc);
    if (s == 0) {
        float b = ld1(ab1, hd, m);
        for (int j = 0; j < 256; ++j)
            b += ld1(aW1, (long)hd * 256 + j, m) * ld1(Wsb, j, m);
        b1p[hd] = b;
    }
}

// ---------------- x8: fp8 copy of h ----------------
__global__ __launch_bounds__(256) void x8_k(const void* __restrict__ h,
                                            unsigned char* __restrict__ X8,
                                            const int* __restrict__ mflag)
{
    const int m = *mflag;
    long t = (long)blockIdx.x * 256 + threadIdx.x;
    long base = t * 8;
    float f[8];
    if (m) {
        float4 a = *(const float4*)((const float*)h + base);
        float4 b = *(const float4*)((const float*)h + base + 4);
        f[0] = a.x; f[1] = a.y; f[2] = a.z; f[3] = a.w;
        f[4] = b.x; f[5] = b.y; f[6] = b.z; f[7] = b.w;
    } else {
        ushort4 a = *(const ushort4*)((const u16*)h + base);
        ushort4 b = *(const ushort4*)((const u16*)h + base + 4);
        f[0] = b2f(a.x); f[1] = b2f(a.y); f[2] = b2f(a.z); f[3] = b2f(a.w);
        f[4] = b2f(b.x); f[5] = b2f(b.y); f[6] = b2f(b.z); f[7] = b2f(b.w);
    }
    unsigned w0 = (unsigned)enc2(f[0], f[1]) | ((unsigned)enc2(f[2], f[3]) << 16);
    unsigned w1 = (unsigned)enc2(f[4], f[5]) | ((unsigned)enc2(f[6], f[7]) << 16);
    *(uint2*)(X8 + base) = make_uint2(w0, w1);
}

// ---------------- combined PQ GEMM -> fp8, XCD-swizzled ----------------
// 5 col-blocks per row-block, same-XCD for L2 A-reuse.
__global__ __launch_bounds__(256) void gemm8_k(
    const void* __restrict__ A,            // h, lda=640
    const u16* __restrict__ W00T,          // 256x256
    const u16* __restrict__ Bq,            // 384x384
    unsigned char* __restrict__ PQ8,
    float s00, float s11, const int* __restrict__ mflag)
{
    const int m = *mflag;
    __shared__ __align__(16) u16 As[128][40];
    __shared__ __align__(16) u16 Bs[128][40];
    int bid = blockIdx.x;
    int x = bid & 7, s = bid >> 3;
    int rb = (s / 5) * 8 + x, cb = s % 5;
    if (rb >= 391) return;
    int K, aoff, col0, ldb, bcol0; const u16* Bt; float scale;
    if (cb < 2) { K = 256; aoff = 0;   col0 = cb * 128;         bcol0 = cb * 128;       Bt = W00T; ldb = 256; scale = s00; }
    else        { K = 384; aoff = 256; col0 = 256 + (cb-2)*128; bcol0 = (cb - 2) * 128; Bt = Bq;   ldb = 384; scale = s11; }
    int tid = threadIdx.x;
    int lane = tid & 63, wave = tid >> 6;
    int wm = (wave & 1) * 64, wn = (wave >> 1) * 64;
    int lm = lane & 15, quad = lane >> 4;
    int bm0 = rb * 128;
    f32x4 acc[4][4] = {};
    int r = tid >> 2, c = tid & 3;
    for (int k0 = 0; k0 < K; k0 += 32) {
#pragma unroll
        for (int p = 0; p < 2; ++p) {
            int row = p * 64 + r;
            int grow = bm0 + row;
            u16 tmp[8];
            if (grow < NNODE) {
                long base = (long)grow * 640 + aoff + k0 + c * 8;
                if (m) {
                    float4 a0 = *(const float4*)((const float*)A + base);
                    float4 a1 = *(const float4*)((const float*)A + base + 4);
                    tmp[0] = f2b(a0.x); tmp[1] = f2b(a0.y); tmp[2] = f2b(a0.z); tmp[3] = f2b(a0.w);
                    tmp[4] = f2b(a1.x); tmp[5] = f2b(a1.y); tmp[6] = f2b(a1.z); tmp[7] = f2b(a1.w);
                } else {
                    *(ushort4*)&tmp[0] = *(const ushort4*)((const u16*)A + base);
                    *(ushort4*)&tmp[4] = *(const ushort4*)((const u16*)A + base + 4);
                }
            } else {
#pragma unroll
                for (int j = 0; j < 8; ++j) tmp[j] = 0;
            }
            *(ushort4*)&As[row][c * 8]     = *(ushort4*)&tmp[0];
            *(ushort4*)&As[row][c * 8 + 4] = *(ushort4*)&tmp[4];
            long bb = (long)(bcol0 + row) * ldb + k0 + c * 8;
            *(ushort4*)&Bs[row][c * 8]     = *(const ushort4*)(Bt + bb);
            *(ushort4*)&Bs[row][c * 8 + 4] = *(const ushort4*)(Bt + bb + 4);
        }
        __syncthreads();
        s16x8 af[4], bfr[4];
#pragma unroll
        for (int t = 0; t < 4; ++t) {
            af[t]  = *(const s16x8*)&As[wm + t * 16 + lm][quad * 8];
            bfr[t] = *(const s16x8*)&Bs[wn + t * 16 + lm][quad * 8];
        }
#pragma unroll
        for (int i = 0; i < 4; ++i)
#pragma unroll
            for (int j = 0; j < 4; ++j)
                acc[i][j] = mfma_bf16(af[i], bfr[j], acc[i][j]);
        __syncthreads();
    }
#pragma unroll
    for (int j = 0; j < 4; ++j) {
        int col = col0 + wn + j * 16 + lm;
#pragma unroll
        for (int i = 0; i < 4; ++i)
#pragma unroll
            for (int rr = 0; rr < 4; ++rr) {
                int grow = bm0 + wm + i * 16 + quad * 4 + rr;
                if (grow < NNODE)
                    PQ8[(long)grow * 640 + col] = enc1(scale * acc[i][j][rr]);
            }
    }
}

// ---------------- atom MLP layer1 (no splits, 20 KB LDS, XCD swizzle) ----------------
__global__ __launch_bounds__(256) void mlp_l1_k(
    const void* __restrict__ A,
    const u16* __restrict__ Bh, const float* __restrict__ b1p,
    u16* __restrict__ hid, const int* __restrict__ mflag)
{
    const int m = *mflag;
    __shared__ __align__(16) u16 Ah[128][40];
    __shared__ __align__(16) u16 Bsh[128][40];
    int bid = blockIdx.x;
    int x = bid & 7, s = bid >> 3;
    int rb = (s >> 1) * 8 + x, cb = s & 1;
    if (rb >= 391) return;
    int tid = threadIdx.x;
    int lane = tid & 63, wave = tid >> 6;
    int wm = (wave & 1) * 64, wn = (wave >> 1) * 64;
    int lm = lane & 15, quad = lane >> 4;
    int bm0 = rb * 128, bn0 = cb * 128;
    f32x4 acc[4][4] = {};
    int r = tid >> 2, c = tid & 3;
    for (int k0 = 0; k0 < 256; k0 += 32) {
#pragma unroll
        for (int p = 0; p < 2; ++p) {
            int row = p * 64 + r;
            int grow = bm0 + row;
            u16 th[8];
            if (grow < NNODE) {
                long base = (long)grow * 640 + k0 + c * 8;
                if (m) {
                    float4 a0 = *(const float4*)((const float*)A + base);
                    float4 a1 = *(const float4*)((const float*)A + base + 4);
                    th[0] = f2b(a0.x); th[1] = f2b(a0.y); th[2] = f2b(a0.z); th[3] = f2b(a0.w);
                    th[4] = f2b(a1.x); th[5] = f2b(a1.y); th[6] = f2b(a1.z); th[7] = f2b(a1.w);
                } else {
                    *(ushort4*)&th[0] = *(const ushort4*)((const u16*)A + base);
                    *(ushort4*)&th[4] = *(const ushort4*)((const u16*)A + base + 4);
                }
            } else {
#pragma unroll
                for (int j = 0; j < 8; ++j) th[j] = 0;
            }
            *(ushort4*)&Ah[row][c * 8]     = *(ushort4*)&th[0];
            *(ushort4*)&Ah[row][c * 8 + 4] = *(ushort4*)&th[4];
            long bb = (long)(bn0 + row) * 256 + k0 + c * 8;
            *(ushort4*)&Bsh[row][c * 8]     = *(const ushort4*)(Bh + bb);
            *(ushort4*)&Bsh[row][c * 8 + 4] = *(const ushort4*)(Bh + bb + 4);
        }
        __syncthreads();
        s16x8 af[4], bfh[4];
#pragma unroll
        for (int t = 0; t < 4; ++t) {
            af[t]  = *(const s16x8*)&Ah[wm + t * 16 + lm][quad * 8];
            bfh[t] = *(const s16x8*)&Bsh[wn + t * 16 + lm][quad * 8];
        }
#pragma unroll
        for (int i = 0; i < 4; ++i)
#pragma unroll
            for (int j = 0; j < 4; ++j)
                acc[i][j] = mfma_bf16(af[i], bfh[j], acc[i][j]);
        __syncthreads();
    }
#pragma unroll
    for (int j = 0; j < 4; ++j) {
        int col = bn0 + wn + j * 16 + lm;
        float bb = b1p[col];
#pragma unroll
        for (int i = 0; i < 4; ++i)
#pragma unroll
            for (int rr = 0; rr < 4; ++rr) {
                int grow = bm0 + wm + i * 16 + quad * 4 + rr;
                if (grow < NNODE)
                    hid[(long)grow * 256 + col] = f2b(silu(acc[i][j][rr] + bb));
            }
    }
}

// ---------------- atom MLP layer2: wave per 16-row tile, no LDS ----------------
__global__ __launch_bounds__(256) void mlp_l2_k(
    const u16* __restrict__ hid, const u16* __restrict__ W2h,
    const void* __restrict__ b2v, void* __restrict__ out,
    const int* __restrict__ mflag)
{
    const int m = *mflag;
    int tid = threadIdx.x, lane = tid & 63, w = tid >> 6;
    int lm = lane & 15, quad = lane >> 4;
    int m0 = blockIdx.x * 64 + w * 16;
    int arow = m0 + lm; if (arow >= NNODE) arow = NNODE - 1;
    const u16* ap = hid + (long)arow * 256;
    const u16* wp = W2h + (long)lm * 256;
    f32x4 acc = {0.f, 0.f, 0.f, 0.f};
#pragma unroll
    for (int k0 = 0; k0 < 256; k0 += 32) {
        s16x8 a  = *(const s16x8*)(ap + k0 + quad * 8);
        s16x8 bh = *(const s16x8*)(wp + k0 + quad * 8);
        acc = mfma_bf16(a, bh, acc);
    }
    float b2 = ld1(b2v, lm, m);
#pragma unroll
    for (int rr = 0; rr < 4; ++rr) {
        int grow = m0 + quad * 4 + rr;
        if (grow < NNODE)
            stout(out, (long)grow * 16 + lm, acc[rr] + b2, m);
    }
}

// ---------------- fused bond head: silu(e@W1^T + tp*w1tp + b1) @ W2^T + b2 ----------------
// 256 edges/block, 4 waves x 4 groups of 16 edges. W1 in LDS; l2 via shfl_xor.
__global__ __launch_bounds__(256) void bond_fused_k(
    const void* __restrict__ A, const u16* __restrict__ W1e,
    const void* __restrict__ b1v, const u16* __restrict__ W2bh,
    const void* __restrict__ b2v, const float* __restrict__ tp,
    const float* __restrict__ w1tp, void* __restrict__ out, long obase,
    const int* __restrict__ mflag)
{
    const int m = *mflag;
    __shared__ __align__(16) u16 W1s[256][72];
    int tid = threadIdx.x;
    int lane = tid & 63, w = tid >> 6;
    int lm = lane & 15, quad = lane >> 4;
#pragma unroll
    for (int i = 0; i < 8; ++i) {              // stage W1 256x64
        int idx = i * 256 + tid;
        int row = idx >> 3, k = (idx & 7) * 8;
        *(ushort4*)&W1s[row][k]     = *(const ushort4*)(W1e + row * 64 + k);
        *(ushort4*)&W1s[row][k + 4] = *(const ushort4*)(W1e + row * 64 + k + 4);
    }
    unsigned w2p[5][8];
#pragma unroll
    for (int o = 0; o < 5; ++o)
#pragma unroll
        for (int t8 = 0; t8 < 8; ++t8) {
            unsigned lo = W2bh[o * 256 + t8 * 32 + lm];
            unsigned hi = W2bh[o * 256 + t8 * 32 + 16 + lm];
            w2p[o][t8] = lo | (hi << 16);
        }
    float b1c[16], wtc[16];
#pragma unroll
    for (int tn = 0; tn < 16; ++tn) {
        b1c[tn] = ld1(b1v, tn * 16 + lm, m);
        wtc[tn] = w1tp[tn * 16 + lm];
    }
    __syncthreads();
    for (int g = 0; g < 4; ++g) {
        int e0 = blockIdx.x * 256 + w * 64 + g * 16;
        if (e0 >= NEDGE) continue;
        s16x8 af0, af1;
        long base = (long)(e0 + lm) * 64 + quad * 8;
        if (m) {
            const float* ap = (const float*)A + base;
            float4 a0 = *(const float4*)ap,        a1 = *(const float4*)(ap + 4);
            float4 a2 = *(const float4*)(ap + 32), a3 = *(const float4*)(ap + 36);
            u16 t0[8] = {f2b(a0.x), f2b(a0.y), f2b(a0.z), f2b(a0.w),
                         f2b(a1.x), f2b(a1.y), f2b(a1.z), f2b(a1.w)};
            u16 t1[8] = {f2b(a2.x), f2b(a2.y), f2b(a2.z), f2b(a2.w),
                         f2b(a3.x), f2b(a3.y), f2b(a3.z), f2b(a3.w)};
            af0 = *(const s16x8*)t0; af1 = *(const s16x8*)t1;
        } else {
            af0 = *(const s16x8*)((const u16*)A + base);
            af1 = *(const s16x8*)((const u16*)A + base + 32);
        }
        f32x4 acc[16] = {};
#pragma unroll
        for (int tn = 0; tn < 16; ++tn) {
            s16x8 b0 = *(const s16x8*)&W1s[tn * 16 + lm][quad * 8];
            s16x8 b1f = *(const s16x8*)&W1s[tn * 16 + lm][32 + quad * 8];
            acc[tn] = mfma_bf16(af0, b0, acc[tn]);
            acc[tn] = mfma_bf16(af1, b1f, acc[tn]);
        }
        float4 tpv = *(const float4*)(tp + e0 + quad * 4);
        float tpr[4] = {tpv.x, tpv.y, tpv.z, tpv.w};
        float sacc[5][4] = {};
#pragma unroll
        for (int tn = 0; tn < 16; ++tn) {
            float hv[4];
#pragma unroll
            for (int rr = 0; rr < 4; ++rr)
                hv[rr] = silu(acc[tn][rr] + b1c[tn] + tpr[rr] * wtc[tn]);
#pragma unroll
            for (int o = 0; o < 5; ++o) {
                unsigned pw = w2p[o][tn >> 1];
                float wv = b2f((u16)((tn & 1) ? (pw >> 16) : (pw & 0xFFFF)));
#pragma unroll
                for (int rr = 0; rr < 4; ++rr)
                    sacc[o][rr] += hv[rr] * wv;
            }
        }
#pragma unroll
        for (int st = 1; st < 16; st <<= 1)
#pragma unroll
            for (int o = 0; o < 5; ++o)
#pragma unroll
                for (int rr = 0; rr < 4; ++rr)
                    sacc[o][rr] += __shfl_xor(sacc[o][rr], st, 64);
#pragma unroll
        for (int o = 0; o < 5; ++o) {
            if (lm == o) {
                float b2 = ld1(b2v, o, m);
#pragma unroll
                for (int rr = 0; rr < 4; ++rr) {
                    int e = e0 + quad * 4 + rr;
                    stout(out, obase + (long)e * 5 + o, sacc[o][rr] + b2, m);
                }
            }
        }
    }
}

// ---------------- tp: wave-per-edge fp8 640-dot ----------------
__global__ __launch_bounds__(256) void tp_k(
    const int* __restrict__ ei, const unsigned char* __restrict__ PQ8,
    const unsigned char* __restrict__ X8, float* __restrict__ tp)
{
    int wave = threadIdx.x >> 6, lane = threadIdx.x & 63;
    int e = blockIdx.x * 4 + wave;
    if (e >= NEDGE) return;
    int row = ei[e], col = ei[NEDGE + e];
    const unsigned char* pq = PQ8 + (long)row * 640;
    const unsigned char* xp = X8 + (long)col * 640;
    uint2 pw = *(const uint2*)(pq + lane * 8);
    uint2 xw = *(const uint2*)(xp + lane * 8);
    unsigned pt = *(const unsigned short*)(pq + 512 + lane * 2);
    unsigned xt = *(const unsigned short*)(xp + 512 + lane * 2);
    float acc = 0.f;
    acc = dot8(pw.x, xw.x, acc);
    acc = dot8(pw.y, xw.y, acc);
    acc = dot2(pt, xt, acc);
#pragma unroll
    for (int off = 32; off > 0; off >>= 1) acc += __shfl_down(acc, off);
    if (lane == 0) tp[e] = acc * 0.0625f;
}

// ---------------- r0 ----------------
__global__ __launch_bounds__(256) void r0_k(
    const void* __restrict__ h, const float* __restrict__ w_eff,
    void* __restrict__ out, const int* __restrict__ mflag)
{
    const int m = *mflag;
    int tid = threadIdx.x, lane = tid & 63, wave = tid >> 6;
    int half = lane >> 5, l32 = lane & 31;
    int node = blockIdx.x * 8 + wave * 2 + half;
    if (node >= NNODE) return;
    long base = (long)node * 640 + 256 + l32 * 12;
    float xv[12];
    if (m) {
        float4 a = *(const float4*)((const float*)h + base);
        float4 b = *(const float4*)((const float*)h + base + 4);
        float4 cc = *(const float4*)((const float*)h + base + 8);
        xv[0]=a.x; xv[1]=a.y; xv[2]=a.z; xv[3]=a.w;
        xv[4]=b.x; xv[5]=b.y; xv[6]=b.z; xv[7]=b.w;
        xv[8]=cc.x; xv[9]=cc.y; xv[10]=cc.z; xv[11]=cc.w;
    } else {
        ushort4 a = *(const ushort4*)((const u16*)h + base);
        ushort4 b = *(const ushort4*)((const u16*)h + base + 4);
        ushort4 cc = *(const ushort4*)((const u16*)h + base + 8);
        xv[0]=b2f(a.x); xv[1]=b2f(a.y); xv[2]=b2f(a.z); xv[3]=b2f(a.w);
        xv[4]=b2f(b.x); xv[5]=b2f(b.y); xv[6]=b2f(b.z); xv[7]=b2f(b.w);
        xv[8]=b2f(cc.x); xv[9]=b2f(cc.y); xv[10]=b2f(cc.z); xv[11]=b2f(cc.w);
    }
    float4 wv = *(const float4*)(w_eff + l32 * 4);
    float s0 = xv[0]*wv.x + xv[3]*wv.y + xv[6]*wv.z + xv[9]*wv.w;
    float s1 = xv[1]*wv.x + xv[4]*wv.y + xv[7]*wv.z + xv[10]*wv.w;
    float s2 = xv[2]*wv.x + xv[5]*wv.y + xv[8]*wv.z + xv[11]*wv.w;
#pragma unroll
    for (int off = 16; off > 0; off >>= 1) {
        s0 += __shfl_down(s0, off, 32);
        s1 += __shfl_down(s1, off, 32);
        s2 += __shfl_down(s2, off, 32);
    }
    if (l32 == 0) {
        stout(out, 800000L + (long)node * 3 + 0, s0, m);
        stout(out, 800000L + (long)node * 3 + 1, s1, m);
        stout(out, 800000L + (long)node * 3 + 2, s2, m);
    }
}

extern "C" void kernel_launch(void* const* d_in, const int* in_sizes, int n_in,
                              void* d_out, int out_size, void* d_ws, size_t ws_size,
                              hipStream_t stream) {
    (void)in_sizes; (void)n_in; (void)out_size; (void)ws_size;
    const void* h      = d_in[0];
    const void* e_fin  = d_in[1];
    const int*  ei     = (const int*)d_in[4];
    const void* Ws_w   = d_in[5];
    const void* Ws_b   = d_in[6];
    const void* Wv     = d_in[7];
    const void* Wcoord = d_in[8];
    const void* W00    = d_in[9];
    const void* W11    = d_in[10];
    const void* aW1    = d_in[11];
    const void* ab1    = d_in[12];
    const void* aW2    = d_in[13];
    const void* ab2    = d_in[14];
    const void* bW1    = d_in[15];
    const void* bb1    = d_in[16];
    const void* bW2    = d_in[17];
    const void* bb2    = d_in[18];

    char* ws = (char*)d_ws;
    int*   mflag = (int*)(ws + 0);
    float* w1tp  = (float*)(ws + 512);
    float* w_eff = (float*)(ws + 2048);
    float* b1p   = (float*)(ws + 3072);
    u16*   W00T  = (u16*)(ws + 4096);
    u16*   W1eh  = (u16*)(ws + 135168);
    u16*   W1sh  = (u16*)(ws + 200704);
    u16*   W2ah  = (u16*)(ws + 462848);
    u16*   W2bh  = (u16*)(ws + 479232);
    u16*   Bq    = (u16*)(ws + 495616);
    float* tp    = (float*)(ws + 790528);
    char*  R     = ws + 1591296;
    u16*           hidA = (u16*)R;                          // 25.6 MB
    unsigned char* PQ8  = (unsigned char*)R;                // 32 MB
    unsigned char* X8   = (unsigned char*)(R + 33554432);   // 32 MB

    detect_k<<<1, 256, 0, stream>>>(h, mflag);
    prep_misc_k<<<930, 256, 0, stream>>>(W00, W11, bW1, Wv, Wcoord, aW2, bW2,
                                         W00T, W1eh, w1tp, w_eff,
                                         W2ah, W2bh, Bq, mflag);
    prep_w1s_k<<<256, 256, 0, stream>>>(aW1, Ws_w, Ws_b, ab1, W1sh, b1p, mflag);

    // ---- atom head (R as hidA) ----
    mlp_l1_k<<<784, 256, 0, stream>>>(h, W1sh, b1p, hidA, mflag);
    mlp_l2_k<<<782, 256, 0, stream>>>(hidA, W2ah, ab2, d_out, mflag);
    // ---- r0 ----
    r0_k<<<6250, 256, 0, stream>>>(h, w_eff, d_out, mflag);

    // ---- PQ8 (overwrites hidA) + X8 ----
    gemm8_k<<<1960, 256, 0, stream>>>(h, W00T, Bq, PQ8,
                                      16.f * INV_SQRT_FAN,
                                      16.f * INV_SQRT_FAN * INV_SQRT3, mflag);
    x8_k<<<15625, 256, 0, stream>>>(h, X8, mflag);
    tp_k<<<50000, 256, 0, stream>>>(ei, PQ8, X8, tp);

    // ---- fused bond head ----
    bond_fused_k<<<782, 256, 0, stream>>>(e_fin, W1eh, bb1, W2bh, bb2,
                                          tp, w1tp, d_out, 950000L, mflag);
}

// Round 6
// 565.175 us; speedup vs baseline: 1.5845x; 1.0537x over previous
//
#include <hip/hip_runtime.h>

typedef unsigned short u16;
typedef float f32x4 __attribute__((ext_vector_type(4)));
typedef float f32x2 __attribute__((ext_vector_type(2)));
typedef short s16x8 __attribute__((ext_vector_type(8)));
typedef __bf16 bf16x8 __attribute__((ext_vector_type(8)));

#define NNODE 50000
#define NEDGE 200000
#define INV_SQRT3 0.57735026918962576f
#define INV_SQRT_FAN 0.0034938562148434216f  /* 1/sqrt(256^2+128^2) */

__device__ inline float b2f(u16 x) {
    unsigned u = ((unsigned)x) << 16;
    return __builtin_bit_cast(float, u);
}
__device__ inline u16 f2b(float f) {
    unsigned u = __builtin_bit_cast(unsigned, f);
    unsigned r = u + 0x7FFFu + ((u >> 16) & 1u);
    return (u16)(r >> 16);
}
__device__ inline float silu(float v) { return v / (1.f + __expf(-v)); }

__device__ inline float ld1(const void* p, long i, int m) {
    return m ? ((const float*)p)[i] : b2f(((const u16*)p)[i]);
}
__device__ inline void stout(void* o, long i, float v, int m) {
    if (m) ((float*)o)[i] = v; else ((u16*)o)[i] = f2b(v);
}

// ---------------- fp8 e4m3fn codec ----------------
#if defined(__has_builtin)
# if __has_builtin(__builtin_amdgcn_cvt_pk_f32_fp8) && __has_builtin(__builtin_amdgcn_cvt_pk_fp8_f32)
#  define HAVE_FP8 1
# endif
#endif
#ifndef HAVE_FP8
# define HAVE_FP8 0
#endif

__device__ inline int f2e4m3_soft(float f) {
    unsigned u = __builtin_bit_cast(unsigned, f);
    int s = (u >> 24) & 0x80;
    float a = __builtin_fabsf(f);
    if (a >= 464.f) return s | 0x7E;
    if (a < 0.015625f) {
        int q = (int)(a * 512.f + 0.5f);
        return s | q;
    }
    int e = (int)((u >> 23) & 0xFF) - 127;
    unsigned m = u & 0x7FFFFF;
    unsigned mq = (m + 0x80000) >> 20;
    if (mq == 8) { mq = 0; e += 1; }
    if (e > 8) return s | 0x7E;
    return s | ((e + 7) << 3) | (int)mq;
}
__device__ inline float e4m3f_soft(int b) {
    int em = b & 0x7F;
    float v;
    if (em >> 3) {
        unsigned bits = ((unsigned)((em >> 3) + 120) << 23) | ((unsigned)(em & 7) << 20);
        v = __builtin_bit_cast(float, bits);
    } else {
        v = (float)em * 0.001953125f;
    }
    return (b & 0x80) ? -v : v;
}
__device__ inline int enc2(float a, float b) {
#if HAVE_FP8
    return __builtin_amdgcn_cvt_pk_fp8_f32(a, b, 0, false) & 0xFFFF;
#else
    return f2e4m3_soft(a) | (f2e4m3_soft(b) << 8);
#endif
}
__device__ inline unsigned char enc1(float a) { return (unsigned char)(enc2(a, a) & 0xFF); }

__device__ inline float dot8(unsigned p, unsigned x, float acc) {
#if HAVE_FP8
    f32x2 p0 = __builtin_amdgcn_cvt_pk_f32_fp8((int)p, false);
    f32x2 p1 = __builtin_amdgcn_cvt_pk_f32_fp8((int)p, true);
    f32x2 x0 = __builtin_amdgcn_cvt_pk_f32_fp8((int)x, false);
    f32x2 x1 = __builtin_amdgcn_cvt_pk_f32_fp8((int)x, true);
    return acc + p0.x * x0.x + p0.y * x0.y + p1.x * x1.x + p1.y * x1.y;
#else
    float r = acc;
#pragma unroll
    for (int i = 0; i < 4; ++i)
        r += e4m3f_soft((p >> (8 * i)) & 0xFF) * e4m3f_soft((x >> (8 * i)) & 0xFF);
    return r;
#endif
}
__device__ inline float dot2(unsigned p, unsigned x, float acc) {
#if HAVE_FP8
    f32x2 p0 = __builtin_amdgcn_cvt_pk_f32_fp8((int)p, false);
    f32x2 x0 = __builtin_amdgcn_cvt_pk_f32_fp8((int)x, false);
    return acc + p0.x * x0.x + p0.y * x0.y;
#else
    return acc + e4m3f_soft(p & 0xFF) * e4m3f_soft(x & 0xFF)
               + e4m3f_soft((p >> 8) & 0xFF) * e4m3f_soft((x >> 8) & 0xFF);
#endif
}

// MFMA wrapper tolerant to either builtin signature.
template <typename V>
__device__ auto mfma_sel(V a, V b, f32x4 c, int)
    -> decltype(__builtin_amdgcn_mfma_f32_16x16x32_bf16(a, b, c, 0, 0, 0)) {
    return __builtin_amdgcn_mfma_f32_16x16x32_bf16(a, b, c, 0, 0, 0);
}
template <typename V>
__device__ f32x4 mfma_sel(V a, V b, f32x4 c, long) {
    bf16x8 aa = __builtin_bit_cast(bf16x8, a);
    bf16x8 bb = __builtin_bit_cast(bf16x8, b);
    return __builtin_amdgcn_mfma_f32_16x16x32_bf16(aa, bb, c, 0, 0, 0);
}
__device__ inline f32x4 mfma_bf16(s16x8 a, s16x8 b, f32x4 c) {
    return mfma_sel(a, b, c, 0);
}

// ---------------- detect input storage dtype ----------------
__global__ __launch_bounds__(256) void detect_k(const void* __restrict__ h, int* __restrict__ flag) {
    int t = threadIdx.x;
    u16 w = ((const u16*)h)[2 * t];
    int tb = (w >> 8) & 0x7F;
    bool pl = (tb >= 0x38 && tb <= 0x41);
    unsigned long long b = __ballot(pl);
    __shared__ int cnt[4];
    if ((t & 63) == 0) cnt[t >> 6] = __popcll(b);
    __syncthreads();
    if (t == 0) {
        int s = cnt[0] + cnt[1] + cnt[2] + cnt[3];
        flag[0] = (s < 128) ? 1 : 0;  // 1 = f32 storage
    }
}

// ---------------- prep: transposes / packs / w_eff ----------------
__global__ __launch_bounds__(256) void prep_misc_k(
    const void* __restrict__ W00, const void* __restrict__ W11,
    const void* __restrict__ bW1, const void* __restrict__ Wv,
    const void* __restrict__ Wcoord, const void* __restrict__ aW2,
    const void* __restrict__ bW2,
    u16* __restrict__ W00T, u16* __restrict__ W1p, u16* __restrict__ W2p,
    float* __restrict__ w1tp, float* __restrict__ w_eff,
    u16* __restrict__ W2ah, u16* __restrict__ W11T,
    const int* __restrict__ mflag)
{
    const int m = *mflag;
    int u = blockIdx.x * 256 + threadIdx.x;
    if (u < 65536) {                 // W00T[j][i] = W00[i][j]
        int j = u >> 8, i = u & 255;
        W00T[u] = f2b(ld1(W00, (long)i * 256 + j, m));
    } else if (u < 81920) {          // W1p: bond W1 fragment pack
        int v = u - 65536;
        int j = v & 7, ln = (v >> 3) & 63, tk = v >> 9;  // tk 0..31
        int tn = tk >> 1, kt = tk & 1;
        int hrow = tn * 16 + (ln & 15);
        int k = kt * 32 + (ln >> 4) * 8 + j;
        W1p[v] = f2b(ld1(bW1, (long)hrow * 65 + 1 + k, m));
    } else if (u < 86016) {          // W2p: bond W2 fragment pack (padded o>=5 -> 0)
        int v = u - 81920;
        int j = v & 7, ln = (v >> 3) & 63, kt = v >> 9;  // kt 0..7
        int o = ln & 15;
        int k = kt * 32 + (ln >> 4) * 8 + j;
        W2p[v] = (o < 5) ? f2b(ld1(bW2, (long)o * 256 + k, m)) : (u16)0;
    } else if (u < 86272) {          // w1tp
        int hd = u - 86016;
        w1tp[hd] = ld1(bW1, (long)hd * 65, m);
    } else if (u < 86400) {          // w_eff
        int c = u - 86272;
        float acc = 0.f;
        for (int d = 0; d < 128; ++d)
            acc += ld1(Wcoord, d, m) * ld1(Wv, (long)d * 128 + c, m);
        w_eff[c] = acc;
    } else if (u < 90496) {          // atom W2 (16x256)
        int v = u - 86400;
        W2ah[v] = f2b(ld1(aW2, v, m));
    } else if (u < 106880) {         // W11T[d][c] = W11[c][d]
        int v = u - 90496;
        int d = v >> 7, c = v & 127;
        W11T[v] = f2b(ld1(W11, (long)c * 128 + d, m));
    }
}

// W1s = atom_W1 @ Ws_w; b1p = atom_W1@Ws_b + atom_b1
__global__ __launch_bounds__(256) void prep_w1s_k(
    const void* __restrict__ aW1, const void* __restrict__ Wsw,
    const void* __restrict__ Wsb, const void* __restrict__ ab1,
    u16* __restrict__ W1sh, float* __restrict__ b1p,
    const int* __restrict__ mflag)
{
    const int m = *mflag;
    int hd = blockIdx.x, s = threadIdx.x;
    float acc = 0.f;
    for (int j = 0; j < 256; ++j)
        acc += ld1(aW1, (long)hd * 256 + j, m) * ld1(Wsw, (long)j * 256 + s, m);
    W1sh[hd * 256 + s] = f2b(acc);
    if (s == 0) {
        float b = ld1(ab1, hd, m);
        for (int j = 0; j < 256; ++j)
            b += ld1(aW1, (long)hd * 256 + j, m) * ld1(Wsb, j, m);
        b1p[hd] = b;
    }
}

// ---------------- pack xv (wave per node) + fused r0 ----------------
__global__ __launch_bounds__(256) void pack_r0_k(
    const void* __restrict__ h, u16* __restrict__ xvp,
    const float* __restrict__ w_eff, void* __restrict__ out,
    const int* __restrict__ mflag)
{
    const int m = *mflag;
    int lane = threadIdx.x & 63, w = threadIdx.x >> 6;
    int node = blockIdx.x * 4 + w;
    if (node >= NNODE) return;
    float a[6];
    if (m) {
        const float* p = (const float*)h + (long)node * 640 + 256 + lane * 6;
        float2 v0 = *(const float2*)p;
        float2 v1 = *(const float2*)(p + 2);
        float2 v2 = *(const float2*)(p + 4);
        a[0] = v0.x; a[1] = v0.y; a[2] = v1.x; a[3] = v1.y; a[4] = v2.x; a[5] = v2.y;
    } else {
        const u16* p = (const u16*)h + (long)node * 640 + 256 + lane * 6;
        ushort2 v0 = *(const ushort2*)p;
        ushort2 v1 = *(const ushort2*)(p + 2);
        ushort2 v2 = *(const ushort2*)(p + 4);
        a[0] = b2f(v0.x); a[1] = b2f(v0.y); a[2] = b2f(v1.x);
        a[3] = b2f(v1.y); a[4] = b2f(v2.x); a[5] = b2f(v2.y);
    }
#pragma unroll
    for (int z = 0; z < 3; ++z) {
        unsigned pk = (unsigned)f2b(a[z]) | ((unsigned)f2b(a[z + 3]) << 16);
        *(unsigned*)(xvp + (long)z * 6400000 + (long)node * 128 + lane * 2) = pk;
    }
    float2 we = *(const float2*)(w_eff + lane * 2);
    float s0 = a[0] * we.x + a[3] * we.y;
    float s1 = a[1] * we.x + a[4] * we.y;
    float s2 = a[2] * we.x + a[5] * we.y;
#pragma unroll
    for (int off = 32; off > 0; off >>= 1) {
        s0 += __shfl_down(s0, off);
        s1 += __shfl_down(s1, off);
        s2 += __shfl_down(s2, off);
    }
    if (lane == 0) {
        stout(out, 800000L + (long)node * 3 + 0, s0, m);
        stout(out, 800000L + (long)node * 3 + 1, s1, m);
        stout(out, 800000L + (long)node * 3 + 2, s2, m);
    }
}

// ---------------- x8: fp8 copy of h ----------------
__global__ __launch_bounds__(256) void x8_k(const void* __restrict__ h,
                                            unsigned char* __restrict__ X8,
                                            const int* __restrict__ mflag)
{
    const int m = *mflag;
    long t = (long)blockIdx.x * 256 + threadIdx.x;
    long base = t * 8;
    float f[8];
    if (m) {
        float4 a = *(const float4*)((const float*)h + base);
        float4 b = *(const float4*)((const float*)h + base + 4);
        f[0] = a.x; f[1] = a.y; f[2] = a.z; f[3] = a.w;
        f[4] = b.x; f[5] = b.y; f[6] = b.z; f[7] = b.w;
    } else {
        ushort4 a = *(const ushort4*)((const u16*)h + base);
        ushort4 b = *(const ushort4*)((const u16*)h + base + 4);
        f[0] = b2f(a.x); f[1] = b2f(a.y); f[2] = b2f(a.z); f[3] = b2f(a.w);
        f[4] = b2f(b.x); f[5] = b2f(b.y); f[6] = b2f(b.z); f[7] = b2f(b.w);
    }
    unsigned w0 = (unsigned)enc2(f[0], f[1]) | ((unsigned)enc2(f[2], f[3]) << 16);
    unsigned w1 = (unsigned)enc2(f[4], f[5]) | ((unsigned)enc2(f[6], f[7]) << 16);
    *(uint2*)(X8 + base) = make_uint2(w0, w1);
}

// ---------------- combined PQ GEMM -> fp8, XCD-swizzled ----------------
// cb 0,1: P = Xs@W00 (K=256). cb 2,3,4: Q_z = xvp_z @ W11 (K=128), interleaved cols.
__global__ __launch_bounds__(256) void gemm8_k(
    const void* __restrict__ h, const u16* __restrict__ xvp,
    const u16* __restrict__ W00T, const u16* __restrict__ W11T,
    unsigned char* __restrict__ PQ8,
    float s00, float s11, const int* __restrict__ mflag)
{
    const int m = *mflag;
    __shared__ __align__(16) u16 As[128][40];
    __shared__ __align__(16) u16 Bs[128][40];
    int bid = blockIdx.x;
    int x = bid & 7, s = bid >> 3;
    int rb = (s / 5) * 8 + x, cb = s % 5;
    if (rb >= 391) return;
    const bool qp = (cb >= 2);
    int z = cb - 2;
    int K = qp ? 128 : 256;
    const u16* Bt = qp ? W11T : W00T;
    int ldb = qp ? 128 : 256;
    int bcol0 = qp ? 0 : cb * 128;
    float scale = qp ? s11 : s00;
    const u16* Aq = xvp + (qp ? (long)z * 6400000 : 0L);
    int tid = threadIdx.x;
    int lane = tid & 63, wave = tid >> 6;
    int wm = (wave & 1) * 64, wn = (wave >> 1) * 64;
    int lm = lane & 15, quad = lane >> 4;
    int bm0 = rb * 128;
    f32x4 acc[4][4] = {};
    int r = tid >> 2, c = tid & 3;
    for (int k0 = 0; k0 < K; k0 += 32) {
#pragma unroll
        for (int p = 0; p < 2; ++p) {
            int row = p * 64 + r;
            int grow = bm0 + row;
            u16 tmp[8];
            if (grow < NNODE) {
                if (qp) {
                    long base = (long)grow * 128 + k0 + c * 8;
                    *(ushort4*)&tmp[0] = *(const ushort4*)(Aq + base);
                    *(ushort4*)&tmp[4] = *(const ushort4*)(Aq + base + 4);
                } else {
                    long base = (long)grow * 640 + k0 + c * 8;
                    if (m) {
                        float4 a0 = *(const float4*)((const float*)h + base);
                        float4 a1 = *(const float4*)((const float*)h + base + 4);
                        tmp[0] = f2b(a0.x); tmp[1] = f2b(a0.y); tmp[2] = f2b(a0.z); tmp[3] = f2b(a0.w);
                        tmp[4] = f2b(a1.x); tmp[5] = f2b(a1.y); tmp[6] = f2b(a1.z); tmp[7] = f2b(a1.w);
                    } else {
                        *(ushort4*)&tmp[0] = *(const ushort4*)((const u16*)h + base);
                        *(ushort4*)&tmp[4] = *(const ushort4*)((const u16*)h + base + 4);
                    }
                }
            } else {
#pragma unroll
                for (int j = 0; j < 8; ++j) tmp[j] = 0;
            }
            *(ushort4*)&As[row][c * 8]     = *(ushort4*)&tmp[0];
            *(ushort4*)&As[row][c * 8 + 4] = *(ushort4*)&tmp[4];
            long bb = (long)(bcol0 + row) * ldb + k0 + c * 8;
            *(ushort4*)&Bs[row][c * 8]     = *(const ushort4*)(Bt + bb);
            *(ushort4*)&Bs[row][c * 8 + 4] = *(const ushort4*)(Bt + bb + 4);
        }
        __syncthreads();
        s16x8 af[4], bfr[4];
#pragma unroll
        for (int t = 0; t < 4; ++t) {
            af[t]  = *(const s16x8*)&As[wm + t * 16 + lm][quad * 8];
            bfr[t] = *(const s16x8*)&Bs[wn + t * 16 + lm][quad * 8];
        }
#pragma unroll
        for (int i = 0; i < 4; ++i)
#pragma unroll
            for (int j = 0; j < 4; ++j)
                acc[i][j] = mfma_bf16(af[i], bfr[j], acc[i][j]);
        __syncthreads();
    }
#pragma unroll
    for (int j = 0; j < 4; ++j) {
        int coln = wn + j * 16 + lm;
        int col = qp ? (256 + 3 * coln + z) : (cb * 128 + coln);
#pragma unroll
        for (int i = 0; i < 4; ++i)
#pragma unroll
            for (int rr = 0; rr < 4; ++rr) {
                int grow = bm0 + wm + i * 16 + quad * 4 + rr;
                if (grow < NNODE)
                    PQ8[(long)grow * 640 + col] = enc1(scale * acc[i][j][rr]);
            }
    }
}

// ---------------- atom MLP layer1 ----------------
__global__ __launch_bounds__(256) void mlp_l1_k(
    const void* __restrict__ A,
    const u16* __restrict__ Bh, const float* __restrict__ b1p,
    u16* __restrict__ hid, const int* __restrict__ mflag)
{
    const int m = *mflag;
    __shared__ __align__(16) u16 Ah[128][40];
    __shared__ __align__(16) u16 Bsh[128][40];
    int bid = blockIdx.x;
    int x = bid & 7, s = bid >> 3;
    int rb = (s >> 1) * 8 + x, cb = s & 1;
    if (rb >= 391) return;
    int tid = threadIdx.x;
    int lane = tid & 63, wave = tid >> 6;
    int wm = (wave & 1) * 64, wn = (wave >> 1) * 64;
    int lm = lane & 15, quad = lane >> 4;
    int bm0 = rb * 128, bn0 = cb * 128;
    f32x4 acc[4][4] = {};
    int r = tid >> 2, c = tid & 3;
    for (int k0 = 0; k0 < 256; k0 += 32) {
#pragma unroll
        for (int p = 0; p < 2; ++p) {
            int row = p * 64 + r;
            int grow = bm0 + row;
            u16 th[8];
            if (grow < NNODE) {
                long base = (long)grow * 640 + k0 + c * 8;
                if (m) {
                    float4 a0 = *(const float4*)((const float*)A + base);
                    float4 a1 = *(const float4*)((const float*)A + base + 4);
                    th[0] = f2b(a0.x); th[1] = f2b(a0.y); th[2] = f2b(a0.z); th[3] = f2b(a0.w);
                    th[4] = f2b(a1.x); th[5] = f2b(a1.y); th[6] = f2b(a1.z); th[7] = f2b(a1.w);
                } else {
                    *(ushort4*)&th[0] = *(const ushort4*)((const u16*)A + base);
                    *(ushort4*)&th[4] = *(const ushort4*)((const u16*)A + base + 4);
                }
            } else {
#pragma unroll
                for (int j = 0; j < 8; ++j) th[j] = 0;
            }
            *(ushort4*)&Ah[row][c * 8]     = *(ushort4*)&th[0];
            *(ushort4*)&Ah[row][c * 8 + 4] = *(ushort4*)&th[4];
            long bb = (long)(bn0 + row) * 256 + k0 + c * 8;
            *(ushort4*)&Bsh[row][c * 8]     = *(const ushort4*)(Bh + bb);
            *(ushort4*)&Bsh[row][c * 8 + 4] = *(const ushort4*)(Bh + bb + 4);
        }
        __syncthreads();
        s16x8 af[4], bfh[4];
#pragma unroll
        for (int t = 0; t < 4; ++t) {
            af[t]  = *(const s16x8*)&Ah[wm + t * 16 + lm][quad * 8];
            bfh[t] = *(const s16x8*)&Bsh[wn + t * 16 + lm][quad * 8];
        }
#pragma unroll
        for (int i = 0; i < 4; ++i)
#pragma unroll
            for (int j = 0; j < 4; ++j)
                acc[i][j] = mfma_bf16(af[i], bfh[j], acc[i][j]);
        __syncthreads();
    }
#pragma unroll
    for (int j = 0; j < 4; ++j) {
        int col = bn0 + wn + j * 16 + lm;
        float bb = b1p[col];
#pragma unroll
        for (int i = 0; i < 4; ++i)
#pragma unroll
            for (int rr = 0; rr < 4; ++rr) {
                int grow = bm0 + wm + i * 16 + quad * 4 + rr;
                if (grow < NNODE)
                    hid[(long)grow * 256 + col] = f2b(silu(acc[i][j][rr] + bb));
            }
    }
}

// ---------------- atom MLP layer2 ----------------
__global__ __launch_bounds__(256) void mlp_l2_k(
    const u16* __restrict__ hid, const u16* __restrict__ W2h,
    const void* __restrict__ b2v, void* __restrict__ out,
    const int* __restrict__ mflag)
{
    const int m = *mflag;
    int tid = threadIdx.x, lane = tid & 63, w = tid >> 6;
    int lm = lane & 15, quad = lane >> 4;
    int m0 = blockIdx.x * 64 + w * 16;
    int arow = m0 + lm; if (arow >= NNODE) arow = NNODE - 1;
    const u16* ap = hid + (long)arow * 256;
    const u16* wp = W2h + (long)lm * 256;
    f32x4 acc = {0.f, 0.f, 0.f, 0.f};
#pragma unroll
    for (int k0 = 0; k0 < 256; k0 += 32) {
        s16x8 a  = *(const s16x8*)(ap + k0 + quad * 8);
        s16x8 bh = *(const s16x8*)(wp + k0 + quad * 8);
        acc = mfma_bf16(a, bh, acc);
    }
    float b2 = ld1(b2v, lm, m);
#pragma unroll
    for (int rr = 0; rr < 4; ++rr) {
        int grow = m0 + quad * 4 + rr;
        if (grow < NNODE)
            stout(out, (long)grow * 16 + lm, acc[rr] + b2, m);
    }
}

// ---------------- bond head v2: MFMA both layers, per-wave LDS transpose ----------------
// wave = 16 edges. l1: 32 MFMA (W1p frags). silu -> LDS -> A-frags. l2: 8 MFMA (W2p frags).
__global__ __launch_bounds__(256) void bond_fused_k(
    const void* __restrict__ A, const u16* __restrict__ W1p,
    const void* __restrict__ b1v, const u16* __restrict__ W2p,
    const void* __restrict__ b2v, const float* __restrict__ tp,
    const float* __restrict__ w1tp, void* __restrict__ out, long obase,
    const int* __restrict__ mflag)
{
    const int m = *mflag;
    __shared__ __align__(16) u16 hidS[4][16][264];
    int tid = threadIdx.x, lane = tid & 63, w = tid >> 6;
    int lm = lane & 15, quad = lane >> 4;
    int e0 = (blockIdx.x * 4 + w) * 16;
    // A fragments (edges m=lm, k = quad*8..+7 [+32])
    s16x8 af0, af1;
    long base = (long)(e0 + lm) * 64 + quad * 8;
    if (m) {
        const float* ap = (const float*)A + base;
        float4 a0 = *(const float4*)ap,        a1 = *(const float4*)(ap + 4);
        float4 a2 = *(const float4*)(ap + 32), a3 = *(const float4*)(ap + 36);
        u16 t0[8] = {f2b(a0.x), f2b(a0.y), f2b(a0.z), f2b(a0.w),
                     f2b(a1.x), f2b(a1.y), f2b(a1.z), f2b(a1.w)};
        u16 t1[8] = {f2b(a2.x), f2b(a2.y), f2b(a2.z), f2b(a2.w),
                     f2b(a3.x), f2b(a3.y), f2b(a3.z), f2b(a3.w)};
        af0 = *(const s16x8*)t0; af1 = *(const s16x8*)t1;
    } else {
        af0 = *(const s16x8*)((const u16*)A + base);
        af1 = *(const s16x8*)((const u16*)A + base + 32);
    }
    float4 tpv = *(const float4*)(tp + e0 + quad * 4);
    float tpr[4] = {tpv.x, tpv.y, tpv.z, tpv.w};
    // layer 1: D[edge][hidden], C-layout: row=quad*4+rr=edge, col=tn*16+lm=hidden
    f32x4 acc1[16];
#pragma unroll
    for (int tn = 0; tn < 16; ++tn) {
        s16x8 b0 = *(const s16x8*)(W1p + ((tn * 2 + 0) * 64 + lane) * 8);
        s16x8 b1f = *(const s16x8*)(W1p + ((tn * 2 + 1) * 64 + lane) * 8);
        f32x4 a = {0.f, 0.f, 0.f, 0.f};
        a = mfma_bf16(af0, b0, a);
        a = mfma_bf16(af1, b1f, a);
        acc1[tn] = a;
    }
    // silu + write per-wave LDS tile hid[edge][h]
#pragma unroll
    for (int tn = 0; tn < 16; ++tn) {
        int hcol = tn * 16 + lm;
        float bb = ld1(b1v, hcol, m);
        float wt = w1tp[hcol];
#pragma unroll
        for (int rr = 0; rr < 4; ++rr)
            hidS[w][quad * 4 + rr][hcol] = f2b(silu(acc1[tn][rr] + bb + tpr[rr] * wt));
    }
    // layer 2: A = hid (m=edge=lm, k=h), B = W2p (n=o). C: row=edge, col=o.
    f32x4 acc2 = {0.f, 0.f, 0.f, 0.f};
#pragma unroll
    for (int kt = 0; kt < 8; ++kt) {
        s16x8 a = *(const s16x8*)&hidS[w][lm][kt * 32 + quad * 8];
        s16x8 b = *(const s16x8*)(W2p + (kt * 64 + lane) * 8);
        acc2 = mfma_bf16(a, b, acc2);
    }
    if (lm < 5) {
        float b2 = ld1(b2v, lm, m);
#pragma unroll
        for (int rr = 0; rr < 4; ++rr) {
            int e = e0 + quad * 4 + rr;
            stout(out, obase + (long)e * 5 + lm, acc2[rr] + b2, m);
        }
    }
}

// ---------------- tp: wave-per-edge fp8 640-dot ----------------
__global__ __launch_bounds__(256) void tp_k(
    const int* __restrict__ ei, const unsigned char* __restrict__ PQ8,
    const unsigned char* __restrict__ X8, float* __restrict__ tp)
{
    int wave = threadIdx.x >> 6, lane = threadIdx.x & 63;
    int e = blockIdx.x * 4 + wave;
    if (e >= NEDGE) return;
    int row = ei[e], col = ei[NEDGE + e];
    const unsigned char* pq = PQ8 + (long)row * 640;
    const unsigned char* xp = X8 + (long)col * 640;
    uint2 pw = *(const uint2*)(pq + lane * 8);
    uint2 xw = *(const uint2*)(xp + lane * 8);
    unsigned pt = *(const unsigned short*)(pq + 512 + lane * 2);
    unsigned xt = *(const unsigned short*)(xp + 512 + lane * 2);
    float acc = 0.f;
    acc = dot8(pw.x, xw.x, acc);
    acc = dot8(pw.y, xw.y, acc);
    acc = dot2(pt, xt, acc);
#pragma unroll
    for (int off = 32; off > 0; off >>= 1) acc += __shfl_down(acc, off);
    if (lane == 0) tp[e] = acc * 0.0625f;
}

extern "C" void kernel_launch(void* const* d_in, const int* in_sizes, int n_in,
                              void* d_out, int out_size, void* d_ws, size_t ws_size,
                              hipStream_t stream) {
    (void)in_sizes; (void)n_in; (void)out_size; (void)ws_size;
    const void* h      = d_in[0];
    const void* e_fin  = d_in[1];
    const int*  ei     = (const int*)d_in[4];
    const void* Ws_w   = d_in[5];
    const void* Ws_b   = d_in[6];
    const void* Wv     = d_in[7];
    const void* Wcoord = d_in[8];
    const void* W00    = d_in[9];
    const void* W11    = d_in[10];
    const void* aW1    = d_in[11];
    const void* ab1    = d_in[12];
    const void* aW2    = d_in[13];
    const void* ab2    = d_in[14];
    const void* bW1    = d_in[15];
    const void* bb1    = d_in[16];
    const void* bW2    = d_in[17];
    const void* bb2    = d_in[18];

    char* ws = (char*)d_ws;
    int*   mflag = (int*)(ws + 0);
    float* w1tp  = (float*)(ws + 512);
    float* w_eff = (float*)(ws + 2048);
    float* b1p   = (float*)(ws + 3072);
    u16*   W00T  = (u16*)(ws + 4096);       // -> 135168
    u16*   W1p   = (u16*)(ws + 135168);     // -> 167936
    u16*   W2p   = (u16*)(ws + 167936);     // -> 176128
    u16*   W1sh  = (u16*)(ws + 176128);     // -> 307200
    u16*   W2ah  = (u16*)(ws + 307200);     // -> 315392
    u16*   W11T  = (u16*)(ws + 315392);     // -> 348160
    float* tp    = (float*)(ws + 348160);   // -> 1148160
    char*  R     = ws + 1149184;
    unsigned char* PQ8  = (unsigned char*)R;                // 32 MB
    unsigned char* X8   = (unsigned char*)(R + 33554432);   // 32 MB
    u16*           hidA = (u16*)(R + 67108864);             // 25.6 MB (then xvp)
    u16*           xvp  = (u16*)(R + 67108864);             // 38.4 MB

    detect_k<<<1, 256, 0, stream>>>(h, mflag);
    prep_misc_k<<<418, 256, 0, stream>>>(W00, W11, bW1, Wv, Wcoord, aW2, bW2,
                                         W00T, W1p, W2p, w1tp, w_eff,
                                         W2ah, W11T, mflag);
    prep_w1s_k<<<256, 256, 0, stream>>>(aW1, Ws_w, Ws_b, ab1, W1sh, b1p, mflag);

    // ---- atom head (uses hidA region) ----
    mlp_l1_k<<<784, 256, 0, stream>>>(h, W1sh, b1p, hidA, mflag);
    mlp_l2_k<<<782, 256, 0, stream>>>(hidA, W2ah, ab2, d_out, mflag);

    // ---- pack xv + fused r0 (overwrites hidA region with xvp) ----
    pack_r0_k<<<12500, 256, 0, stream>>>(h, xvp, w_eff, d_out, mflag);

    // ---- PQ8 + X8 ----
    gemm8_k<<<1960, 256, 0, stream>>>(h, xvp, W00T, W11T, PQ8,
                                      16.f * INV_SQRT_FAN,
                                      16.f * INV_SQRT_FAN * INV_SQRT3, mflag);
    x8_k<<<15625, 256, 0, stream>>>(h, X8, mflag);
    tp_k<<<50000, 256, 0, stream>>>(ei, PQ8, X8, tp);

    // ---- bond head (MFMA x2 via per-wave LDS transpose) ----
    bond_fused_k<<<3125, 256, 0, stream>>>(e_fin, W1p, bb1, W2p, bb2,
                                           tp, w1tp, d_out, 950000L, mflag);
}